// Round 5
// baseline (114.967 us; speedup 1.0000x reference)
//
#include <hip/hip_runtime.h>
#include <hip/hip_bf16.h>

#define DIM   1024
#define NSEQ  1024
#define BATCH 2
#define NHEAD 16
#define DH    64

typedef unsigned short u16;
typedef __attribute__((ext_vector_type(8))) short  short8;
typedef __attribute__((ext_vector_type(4))) float  f32x4;
typedef __attribute__((ext_vector_type(8))) unsigned short u16x8;
typedef __attribute__((ext_vector_type(4))) unsigned short u16x4;

// log2(e) / sqrt(DH)
#define EXP_SCALE 0.18033688011112042f

__device__ __forceinline__ u16 f2bf(float f) {
  union { float f; unsigned u; } v; v.f = f;
  unsigned r = v.u + 0x7FFFu + ((v.u >> 16) & 1u);   // RNE
  return (u16)(r >> 16);
}

// ---------------------------------------------------------------------------
// Densify block-circulant weights -> bf16 dense, 8 cols/thread (u16x8 writes).
// Wd[r][c] = w[p][q][(a-b)&7],  r=p*8+a, c=q*8+b.
// ---------------------------------------------------------------------------
__global__ __launch_bounds__(256) void densify_bf16(
    const float* __restrict__ wq, const float* __restrict__ wk,
    const float* __restrict__ wv, const float* __restrict__ wo,
    u16* __restrict__ Wd) {
  const int z = blockIdx.z;
  const float* w = (z == 0) ? wq : (z == 1) ? wk : (z == 2) ? wv : wo;
  u16* out = Wd + (size_t)z * DIM * DIM;
  const int idx8 = blockIdx.x * 256 + threadIdx.x;   // u16x8 index
  const int r  = idx8 >> 7;          // row 0..1023
  const int q  = idx8 & 127;         // col block (c8 == q)
  const int p  = r >> 3, a = r & 7;
  const float* wrow = w + (size_t)(p * 128 + q) * 8;
  const float4 w0 = *(const float4*)(wrow);
  const float4 w1 = *(const float4*)(wrow + 4);
  const float wv8[8] = {w0.x, w0.y, w0.z, w0.w, w1.x, w1.y, w1.z, w1.w};
  u16x8 o;
#pragma unroll
  for (int j = 0; j < 8; ++j) o[j] = f2bf(wv8[(a - j) & 7]);
  ((u16x8*)out)[idx8] = o;
}

// ---------------------------------------------------------------------------
// fp32 -> bf16 conversion, 8 elements/thread
// ---------------------------------------------------------------------------
__global__ __launch_bounds__(256) void cvt_bf16(
    const float* __restrict__ in, u16* __restrict__ out) {
  const int i = blockIdx.x * 256 + threadIdx.x;
  const float4 a = ((const float4*)in)[2 * i];
  const float4 b = ((const float4*)in)[2 * i + 1];
  u16x8 o;
  o[0] = f2bf(a.x); o[1] = f2bf(a.y); o[2] = f2bf(a.z); o[3] = f2bf(a.w);
  o[4] = f2bf(b.x); o[5] = f2bf(b.y); o[6] = f2bf(b.z); o[7] = f2bf(b.w);
  ((u16x8*)out)[i] = o;
}

// ---------------------------------------------------------------------------
// bf16 MFMA GEMM (NT) + bias, 2-phase double-buffered (T3 minimal):
// STAGE(next) -> compute(cur) -> one __syncthreads per K-step.
// 128x128 tile, BK=32, 4 waves. BFOUT=1 -> bf16 output, else fp32.
// ---------------------------------------------------------------------------
template <int BFOUT>
__global__ __launch_bounds__(256) void gemm_bf16_nt(
    const u16* __restrict__ A, const u16* __restrict__ Wbase,
    const float* __restrict__ b0, const float* __restrict__ b1,
    const float* __restrict__ b2,
    void* __restrict__ C0, void* __restrict__ C1, void* __restrict__ C2) {
  const int z = blockIdx.z;
  const u16* W      = Wbase + (size_t)z * DIM * DIM;
  const float* bias = (z == 0) ? b0 : (z == 1) ? b1 : b2;
  void* C           = (z == 0) ? C0 : (z == 1) ? C1 : C2;

  __shared__ u16 As[2][128 * 32];
  __shared__ u16 Bs[2][128 * 32];

  const int tid  = threadIdx.x;
  const int w    = tid >> 6, lane = tid & 63;
  const int mb   = blockIdx.y * 128, nb = blockIdx.x * 128;

  f32x4 acc[4][4] = {};

  const int m0 = (w >> 1) * 64, n0 = (w & 1) * 64;
  const int lr = lane & 15, lk = (lane >> 4) * 8;

  const int cb = w * 2;
  const int c0 = cb * 64 + lane;
  const int c1 = c0 + 64;
  const int row0 = c0 >> 2, kc0 = (c0 & 3) * 8;
  const int row1 = c1 >> 2, kc1 = (c1 & 3) * 8;

  const u16* Ap0 = A + (size_t)(mb + row0) * DIM + kc0;
  const u16* Wp0 = W + (size_t)(nb + row0) * DIM + kc0;
  const u16* Ap1 = A + (size_t)(mb + row1) * DIM + kc1;
  const u16* Wp1 = W + (size_t)(nb + row1) * DIM + kc1;

#define STAGE(buf, k0)                                                         \
  do {                                                                         \
    __builtin_amdgcn_global_load_lds(                                          \
        (const __attribute__((address_space(1))) void*)(Ap0 + (k0)),           \
        (__attribute__((address_space(3))) void*)(As[buf] + cb * 512), 16, 0, 0);\
    __builtin_amdgcn_global_load_lds(                                          \
        (const __attribute__((address_space(1))) void*)(Wp0 + (k0)),           \
        (__attribute__((address_space(3))) void*)(Bs[buf] + cb * 512), 16, 0, 0);\
    __builtin_amdgcn_global_load_lds(                                          \
        (const __attribute__((address_space(1))) void*)(Ap1 + (k0)),           \
        (__attribute__((address_space(3))) void*)(As[buf] + (cb + 1) * 512), 16, 0, 0);\
    __builtin_amdgcn_global_load_lds(                                          \
        (const __attribute__((address_space(1))) void*)(Wp1 + (k0)),           \
        (__attribute__((address_space(3))) void*)(Bs[buf] + (cb + 1) * 512), 16, 0, 0);\
  } while (0)

  STAGE(0, 0);
  __syncthreads();          // drains vmcnt(0): buf0 resident
  int cur = 0;
  for (int k0 = 0; k0 < DIM; k0 += 32) {
    if (k0 + 32 < DIM) STAGE(cur ^ 1, k0 + 32);   // issue next-tile loads

    short8 a[4], b[4];
#pragma unroll
    for (int mi = 0; mi < 4; ++mi)
      a[mi] = *(const short8*)&As[cur][(m0 + mi * 16 + lr) * 32 + lk];
#pragma unroll
    for (int ni = 0; ni < 4; ++ni)
      b[ni] = *(const short8*)&Bs[cur][(n0 + ni * 16 + lr) * 32 + lk];
#pragma unroll
    for (int mi = 0; mi < 4; ++mi)
#pragma unroll
      for (int ni = 0; ni < 4; ++ni)
        acc[mi][ni] = __builtin_amdgcn_mfma_f32_16x16x32_bf16(
            a[mi], b[ni], acc[mi][ni], 0, 0, 0);

    __syncthreads();        // vmcnt(0): next tile resident; reads of cur done
    cur ^= 1;
  }
#undef STAGE

  // epilogue: C/D layout col = lane&15, row = (lane>>4)*4 + j
  const int col = lane & 15, rq = (lane >> 4) * 4;
#pragma unroll
  for (int ni = 0; ni < 4; ++ni) {
    const int gc = nb + n0 + ni * 16 + col;
    const float bv = bias[gc];
#pragma unroll
    for (int mi = 0; mi < 4; ++mi) {
      const size_t rbase = (size_t)(mb + m0 + mi * 16 + rq) * DIM + gc;
#pragma unroll
      for (int j = 0; j < 4; ++j) {
        const float v = acc[mi][ni][j] + bv;
        if (BFOUT) ((u16*)C)[rbase + (size_t)j * DIM] = f2bf(v);
        else       ((float*)C)[rbase + (size_t)j * DIM] = v;
      }
    }
  }
}

// ---------------------------------------------------------------------------
// V transpose: Vb [b][n][DIM] (head slice) -> Vt [b][h][dh=64][NSEQ].
// 8x8 register transpose per thread; fully coalesced 16B loads/stores, no LDS.
// ---------------------------------------------------------------------------
__global__ __launch_bounds__(256) void transpose_v(
    const u16* __restrict__ Vb, u16* __restrict__ Vt) {
  const int n0 = blockIdx.x * 256;
  const int h  = blockIdx.y;
  const int b  = blockIdx.z;
  const int tid = threadIdx.x;
  const int dhb = tid & 7;          // dh block of 8
  const int nb8 = tid >> 3;         // n block of 8 (0..31)

  const u16* src = Vb + ((size_t)(b * NSEQ) + n0 + nb8 * 8) * DIM + h * DH + dhb * 8;
  u16x8 v[8];
#pragma unroll
  for (int i = 0; i < 8; ++i) v[i] = *(const u16x8*)(src + (size_t)i * DIM);

  u16* dst = Vt + ((size_t)(b * NHEAD + h) * DH + dhb * 8) * NSEQ + n0 + nb8 * 8;
#pragma unroll
  for (int j = 0; j < 8; ++j) {
    u16x8 o;
#pragma unroll
    for (int i = 0; i < 8; ++i) o[i] = v[i][j];
    *(u16x8*)(dst + (size_t)j * NSEQ) = o;
  }
}

// ---------------------------------------------------------------------------
// Causal flash attention, bf16 MFMA, no K/V LDS staging (L2-resident, m169),
// no __syncthreads in the loop. 4 waves x 16 queries.
// Swapped QK^T (S^T: col=q=lane&15) -> lane-local softmax.
// PV as O^T = mfma(V^T_frag(global), P_frag(wave-private LDS)).
// K-frags prefetched one tile ahead; V-frags issued before softmax VALU.
// ---------------------------------------------------------------------------
__global__ __launch_bounds__(256) void attn_mfma(
    const u16* __restrict__ Qg, const u16* __restrict__ Kg,
    const u16* __restrict__ Vt, u16* __restrict__ Og) {
  const int qt = 15 - blockIdx.x;          // heavy q-tiles first (LPT)
  const int h  = blockIdx.y;
  const int b  = blockIdx.z;
  const int tid = threadIdx.x;
  const int w  = tid >> 6, l = tid & 63;
  const int lr = l & 15, lg = l >> 4;      // frag row / k-group

  __shared__ u16 Plds[4][16 * 64];         // per-wave P [q][key], XOR-swizzled

  const int qg = qt * 64 + w * 16 + lr;    // this lane's query row
  const size_t base_bh = (size_t)b * NSEQ * DIM + (size_t)h * DH;
  const size_t vt_bh   = (size_t)(b * NHEAD + h) * DH * NSEQ;

  // Q fragments: row=q(lr), k = c*32 + lg*8 .. +8
  short8 qf[2];
#pragma unroll
  for (int c = 0; c < 2; ++c)
    qf[c] = *(const short8*)(Qg + base_bh + (size_t)qg * DIM + c * 32 + lg * 8);

  f32x4 acc_o[4] = {};                     // O^T: col=q(lr), row dh=d*16+lg*4+j
  float m_run = -1e30f, l_run = 0.f;

  char* pbase = (char*)Plds[w];
  const int psw = (lr & 7) << 4;           // P row swizzle (bits 4-6)

  // prefetch K tile 0 fragments
  short8 kf[4][2];
#pragma unroll
  for (int t16 = 0; t16 < 4; ++t16)
#pragma unroll
    for (int c = 0; c < 2; ++c)
      kf[t16][c] = *(const short8*)
          (Kg + base_bh + (size_t)(t16 * 16 + lr) * DIM + c * 32 + lg * 8);

  for (int kt = 0;; ++kt) {
    // --- QK^T: s[t16] = S^T subtile (rows=key, col=q) ---
    f32x4 s[4] = {};
#pragma unroll
    for (int t16 = 0; t16 < 4; ++t16)
#pragma unroll
      for (int c = 0; c < 2; ++c)
        s[t16] = __builtin_amdgcn_mfma_f32_16x16x32_bf16(
            kf[t16][c], qf[c], s[t16], 0, 0, 0);

    // --- issue V-frag loads now (latency hides under softmax VALU) ---
    short8 vf[4][2];
#pragma unroll
    for (int d = 0; d < 4; ++d)
#pragma unroll
      for (int c = 0; c < 2; ++c)
        vf[d][c] = *(const short8*)
            (Vt + vt_bh + (size_t)(d * 16 + lr) * NSEQ + kt * 64 + c * 32 + lg * 8);

    // --- prefetch next K tile ---
    const bool more = kt < qt;
    short8 kfn[4][2];
    if (more) {
#pragma unroll
      for (int t16 = 0; t16 < 4; ++t16)
#pragma unroll
        for (int c = 0; c < 2; ++c)
          kfn[t16][c] = *(const short8*)
              (Kg + base_bh + (size_t)((kt + 1) * 64 + t16 * 16 + lr) * DIM +
               c * 32 + lg * 8);
    }

    // --- mask (diagonal tile only) + online softmax (lane-local q) ---
    const bool diag = (kt == qt);
    float mloc = -1e30f;
#pragma unroll
    for (int t16 = 0; t16 < 4; ++t16)
#pragma unroll
      for (int j = 0; j < 4; ++j) {
        float v = s[t16][j];
        if (diag && (kt * 64 + t16 * 16 + lg * 4 + j) > qg) v = -1e30f;
        s[t16][j] = v;
        mloc = fmaxf(mloc, v);
      }
    mloc = fmaxf(mloc, __shfl_xor(mloc, 16));
    mloc = fmaxf(mloc, __shfl_xor(mloc, 32));
    const float m_new = fmaxf(m_run, mloc);
    const float a = exp2f((m_run - m_new) * EXP_SCALE);
    float psum = 0.f;
    u16x4 pk[4];
#pragma unroll
    for (int t16 = 0; t16 < 4; ++t16)
#pragma unroll
      for (int j = 0; j < 4; ++j) {
        const float p = exp2f((s[t16][j] - m_new) * EXP_SCALE);
        psum += p;
        pk[t16][j] = f2bf(p);
      }
    psum += __shfl_xor(psum, 16);
    psum += __shfl_xor(psum, 32);
    l_run = l_run * a + psum;
    m_run = m_new;
#pragma unroll
    for (int d = 0; d < 4; ++d) acc_o[d] *= a;

    // --- P -> wave-private LDS (swizzled), then PV ---
#pragma unroll
    for (int t16 = 0; t16 < 4; ++t16)
      *(u16x4*)(pbase + lr * 128 + ((t16 * 32 + lg * 8) ^ psw)) = pk[t16];

#pragma unroll
    for (int c = 0; c < 2; ++c) {
      const short8 pf = *(const short8*)
          (pbase + lr * 128 + ((c * 64 + lg * 16) ^ psw));
#pragma unroll
      for (int d = 0; d < 4; ++d)
        acc_o[d] = __builtin_amdgcn_mfma_f32_16x16x32_bf16(
            vf[d][c], pf, acc_o[d], 0, 0, 0);
    }

    if (!more) break;
#pragma unroll
    for (int t16 = 0; t16 < 4; ++t16)
#pragma unroll
      for (int c = 0; c < 2; ++c) kf[t16][c] = kfn[t16][c];
  }

  // --- epilogue: O[q][dh] = acc_o / l_run, bf16 ---
  const float inv = 1.f / l_run;
  u16* Op = Og + (size_t)(b * NSEQ + qg) * DIM + (size_t)h * DH;
#pragma unroll
  for (int d = 0; d < 4; ++d) {
    u16x4 o;
    o[0] = f2bf(acc_o[d][0] * inv); o[1] = f2bf(acc_o[d][1] * inv);
    o[2] = f2bf(acc_o[d][2] * inv); o[3] = f2bf(acc_o[d][3] * inv);
    *(u16x4*)(Op + d * 16 + lg * 4) = o;
  }
}

// ---------------------------------------------------------------------------
extern "C" void kernel_launch(void* const* d_in, const int* in_sizes, int n_in,
                              void* d_out, int out_size, void* d_ws, size_t ws_size,
                              hipStream_t stream) {
  const float* x  = (const float*)d_in[0];
  // d_in[1] = causal mask (ignored; mask is m > n analytically)
  const float* wq = (const float*)d_in[2];
  const float* bq = (const float*)d_in[3];
  const float* wk = (const float*)d_in[4];
  const float* bk = (const float*)d_in[5];
  const float* wv = (const float*)d_in[6];
  const float* bv = (const float*)d_in[7];
  const float* wo = (const float*)d_in[8];
  const float* bo = (const float*)d_in[9];

  char* ws = (char*)d_ws;
  u16* Wd  = (u16*)(ws);                       //  0..8MB  4 dense bf16 W
  u16* Xb  = (u16*)(ws + ((size_t)8  << 20));  //  8..12MB x bf16
  u16* Qb  = (u16*)(ws + ((size_t)12 << 20));  // 12..16MB Q bf16
  u16* Kb  = (u16*)(ws + ((size_t)16 << 20));  // 16..20MB K bf16
  u16* Vb  = (u16*)(ws + ((size_t)20 << 20));  // 20..24MB V bf16
  u16* Vt  = (u16*)(ws + ((size_t)24 << 20));  // 24..28MB V^T bf16
  u16* AOb = (u16*)(ws + ((size_t)28 << 20));  // 28..32MB attn out bf16

  // 1) densify circulant weights to dense bf16 (8 cols/thread)
  densify_bf16<<<dim3(512, 1, 4), 256, 0, stream>>>(wq, wk, wv, wo, Wd);

  // 2) x -> bf16
  cvt_bf16<<<dim3((BATCH * NSEQ * DIM) / (256 * 8), 1, 1), 256, 0, stream>>>(x, Xb);

  // 3) Q/K/V projections (bf16 MFMA, 2-phase dbuf, bf16 out)
  gemm_bf16_nt<1><<<dim3(DIM / 128, (BATCH * NSEQ) / 128, 3), 256, 0, stream>>>(
      Xb, Wd, bq, bk, bv, Qb, Kb, Vb);

  // 4) V -> V^T per (b,h)  [for direct global PV fragment loads]
  transpose_v<<<dim3(NSEQ / 256, NHEAD, BATCH), 256, 0, stream>>>(Vb, Vt);

  // 5) causal attention (bf16 MFMA, no staging, bf16 out)
  attn_mfma<<<dim3(16, 16, 2), 256, 0, stream>>>(Qb, Kb, Vt, AOb);

  // 6) output projection (fp32 out)
  gemm_bf16_nt<0><<<dim3(DIM / 128, (BATCH * NSEQ) / 128, 1), 256, 0, stream>>>(
      AOb, Wd + (size_t)3 * DIM * DIM, bo, bo, bo, d_out, d_out, d_out);
}

// Round 6
// 112.246 us; speedup vs baseline: 1.0242x; 1.0242x over previous
//
#include <hip/hip_runtime.h>
#include <hip/hip_bf16.h>

#define DIM   1024
#define NSEQ  1024
#define BATCH 2
#define NHEAD 16
#define DH    64

typedef unsigned short u16;
typedef __attribute__((ext_vector_type(8))) short  short8;
typedef __attribute__((ext_vector_type(4))) float  f32x4;
typedef __attribute__((ext_vector_type(8))) unsigned short u16x8;
typedef __attribute__((ext_vector_type(4))) unsigned short u16x4;

// log2(e) / sqrt(DH)
#define EXP_SCALE 0.18033688011112042f
// partial slot: 64x64 O (4096) + m (64) + l (64), padded
#define SLOT 4352

__device__ __forceinline__ u16 f2bf(float f) {
  union { float f; unsigned u; } v; v.f = f;
  unsigned r = v.u + 0x7FFFu + ((v.u >> 16) & 1u);   // RNE
  return (u16)(r >> 16);
}

// ---------------------------------------------------------------------------
// Densify block-circulant weights -> bf16 dense, 8 cols/thread.
// ---------------------------------------------------------------------------
__global__ __launch_bounds__(256) void densify_bf16(
    const float* __restrict__ wq, const float* __restrict__ wk,
    const float* __restrict__ wv, const float* __restrict__ wo,
    u16* __restrict__ Wd) {
  const int z = blockIdx.z;
  const float* w = (z == 0) ? wq : (z == 1) ? wk : (z == 2) ? wv : wo;
  u16* out = Wd + (size_t)z * DIM * DIM;
  const int idx8 = blockIdx.x * 256 + threadIdx.x;
  const int r  = idx8 >> 7;
  const int q  = idx8 & 127;
  const int p  = r >> 3, a = r & 7;
  const float* wrow = w + (size_t)(p * 128 + q) * 8;
  const float4 w0 = *(const float4*)(wrow);
  const float4 w1 = *(const float4*)(wrow + 4);
  const float wv8[8] = {w0.x, w0.y, w0.z, w0.w, w1.x, w1.y, w1.z, w1.w};
  u16x8 o;
#pragma unroll
  for (int j = 0; j < 8; ++j) o[j] = f2bf(wv8[(a - j) & 7]);
  ((u16x8*)out)[idx8] = o;
}

// ---------------------------------------------------------------------------
// fp32 -> bf16 conversion, 8 elements/thread
// ---------------------------------------------------------------------------
__global__ __launch_bounds__(256) void cvt_bf16(
    const float* __restrict__ in, u16* __restrict__ out) {
  const int i = blockIdx.x * 256 + threadIdx.x;
  const float4 a = ((const float4*)in)[2 * i];
  const float4 b = ((const float4*)in)[2 * i + 1];
  u16x8 o;
  o[0] = f2bf(a.x); o[1] = f2bf(a.y); o[2] = f2bf(a.z); o[3] = f2bf(a.w);
  o[4] = f2bf(b.x); o[5] = f2bf(b.y); o[6] = f2bf(b.z); o[7] = f2bf(b.w);
  ((u16x8*)out)[i] = o;
}

// ---------------------------------------------------------------------------
// bf16 MFMA GEMM (NT) + bias — Round-4 proven single-buffer m97 structure.
// 128x128 tile, BK=32, 4 waves. BFOUT=1 -> bf16 output, else fp32.
// ---------------------------------------------------------------------------
template <int BFOUT>
__global__ __launch_bounds__(256) void gemm_bf16_nt(
    const u16* __restrict__ A, const u16* __restrict__ Wbase,
    const float* __restrict__ b0, const float* __restrict__ b1,
    const float* __restrict__ b2,
    void* __restrict__ C0, void* __restrict__ C1, void* __restrict__ C2) {
  const int z = blockIdx.z;
  const u16* W      = Wbase + (size_t)z * DIM * DIM;
  const float* bias = (z == 0) ? b0 : (z == 1) ? b1 : b2;
  void* C           = (z == 0) ? C0 : (z == 1) ? C1 : C2;

  __shared__ u16 As[128 * 32];
  __shared__ u16 Bs[128 * 32];

  const int tid  = threadIdx.x;
  const int w    = tid >> 6, lane = tid & 63;
  const int mb   = blockIdx.y * 128, nb = blockIdx.x * 128;

  f32x4 acc[4][4] = {};

  const int m0 = (w >> 1) * 64, n0 = (w & 1) * 64;
  const int lr = lane & 15, lk = (lane >> 4) * 8;

  const int cb = w * 2;
  const int c0 = cb * 64 + lane;
  const int c1 = c0 + 64;
  const int row0 = c0 >> 2, kc0 = (c0 & 3) * 8;
  const int row1 = c1 >> 2, kc1 = (c1 & 3) * 8;

  for (int k0 = 0; k0 < DIM; k0 += 32) {
    __syncthreads();
    __builtin_amdgcn_global_load_lds(
        (const __attribute__((address_space(1))) void*)(A + (size_t)(mb + row0) * DIM + k0 + kc0),
        (__attribute__((address_space(3))) void*)(As + (size_t)cb * 512), 16, 0, 0);
    __builtin_amdgcn_global_load_lds(
        (const __attribute__((address_space(1))) void*)(W + (size_t)(nb + row0) * DIM + k0 + kc0),
        (__attribute__((address_space(3))) void*)(Bs + (size_t)cb * 512), 16, 0, 0);
    __builtin_amdgcn_global_load_lds(
        (const __attribute__((address_space(1))) void*)(A + (size_t)(mb + row1) * DIM + k0 + kc1),
        (__attribute__((address_space(3))) void*)(As + (size_t)(cb + 1) * 512), 16, 0, 0);
    __builtin_amdgcn_global_load_lds(
        (const __attribute__((address_space(1))) void*)(W + (size_t)(nb + row1) * DIM + k0 + kc1),
        (__attribute__((address_space(3))) void*)(Bs + (size_t)(cb + 1) * 512), 16, 0, 0);
    __syncthreads();

    short8 a[4], b[4];
#pragma unroll
    for (int mi = 0; mi < 4; ++mi)
      a[mi] = *(const short8*)&As[(m0 + mi * 16 + lr) * 32 + lk];
#pragma unroll
    for (int ni = 0; ni < 4; ++ni)
      b[ni] = *(const short8*)&Bs[(n0 + ni * 16 + lr) * 32 + lk];
#pragma unroll
    for (int mi = 0; mi < 4; ++mi)
#pragma unroll
      for (int ni = 0; ni < 4; ++ni)
        acc[mi][ni] = __builtin_amdgcn_mfma_f32_16x16x32_bf16(
            a[mi], b[ni], acc[mi][ni], 0, 0, 0);
  }

  const int col = lane & 15, rq = (lane >> 4) * 4;
#pragma unroll
  for (int ni = 0; ni < 4; ++ni) {
    const int gc = nb + n0 + ni * 16 + col;
    const float bv = bias[gc];
#pragma unroll
    for (int mi = 0; mi < 4; ++mi) {
      const size_t rbase = (size_t)(mb + m0 + mi * 16 + rq) * DIM + gc;
#pragma unroll
      for (int j = 0; j < 4; ++j) {
        const float v = acc[mi][ni][j] + bv;
        if (BFOUT) ((u16*)C)[rbase + (size_t)j * DIM] = f2bf(v);
        else       ((float*)C)[rbase + (size_t)j * DIM] = v;
      }
    }
  }
}

// ---------------------------------------------------------------------------
// V transpose: Vb [b][n][DIM] (head slice) -> Vt [b][h][dh=64][NSEQ].
// ---------------------------------------------------------------------------
__global__ __launch_bounds__(256) void transpose_v(
    const u16* __restrict__ Vb, u16* __restrict__ Vt) {
  const int n0 = blockIdx.x * 256;
  const int h  = blockIdx.y;
  const int b  = blockIdx.z;
  const int tid = threadIdx.x;
  const int dhb = tid & 7;
  const int nb8 = tid >> 3;

  const u16* src = Vb + ((size_t)(b * NSEQ) + n0 + nb8 * 8) * DIM + h * DH + dhb * 8;
  u16x8 v[8];
#pragma unroll
  for (int i = 0; i < 8; ++i) v[i] = *(const u16x8*)(src + (size_t)i * DIM);

  u16* dst = Vt + ((size_t)(b * NHEAD + h) * DH + dhb * 8) * NSEQ + n0 + nb8 * 8;
#pragma unroll
  for (int j = 0; j < 8; ++j) {
    u16x8 o;
#pragma unroll
    for (int i = 0; i < 8; ++i) o[i] = v[i][j];
    *(u16x8*)(dst + (size_t)j * NSEQ) = o;
  }
}

// ---------------------------------------------------------------------------
// Split-K causal flash attention (partials). Block = (qt, chunk) x (h, b):
// 64 queries x 256 keys (<=4 KV tiles of 64). 4 waves x 16 q.
// Swapped QK^T -> lane-local softmax; PV via V^T global frags + P in LDS.
// Writes f32 partial O[64][64] + m[64] + l[64] per block.
// ---------------------------------------------------------------------------
__global__ __launch_bounds__(256, 4) void attn_split(
    const u16* __restrict__ Qg, const u16* __restrict__ Kg,
    const u16* __restrict__ Vt, float* __restrict__ Part) {
  // blockIdx.x -> (qt, cc), heavy qt first
  int idx = blockIdx.x, qt = 0, cc = 0;
  for (int t = 15; t >= 0; --t) {
    const int nc = (t >> 2) + 1;
    if (idx < nc) { qt = t; cc = idx; break; }
    idx -= nc;
  }
  const int h = blockIdx.y, b = blockIdx.z;
  const int tid = threadIdx.x;
  const int w  = tid >> 6, l = tid & 63;
  const int lr = l & 15, lg = l >> 4;

  __shared__ u16 Plds[4][16 * 64];

  const int qg = qt * 64 + w * 16 + lr;
  const size_t base_bh = (size_t)b * NSEQ * DIM + (size_t)h * DH;
  const size_t vt_bh   = (size_t)(b * NHEAD + h) * DH * NSEQ;

  short8 qf[2];
#pragma unroll
  for (int c = 0; c < 2; ++c)
    qf[c] = *(const short8*)(Qg + base_bh + (size_t)qg * DIM + c * 32 + lg * 8);

  f32x4 acc_o[4] = {};
  float m_run = -1e30f, l_run = 0.f;
  char* pbase = (char*)Plds[w];
  const int psw = (lr & 7) << 4;

  const int kt_end = min(cc * 4 + 4, qt + 1);

  for (int kt = cc * 4; kt < kt_end; ++kt) {
    // K fragments for this tile
    short8 kf[4][2];
#pragma unroll
    for (int t16 = 0; t16 < 4; ++t16)
#pragma unroll
      for (int c = 0; c < 2; ++c)
        kf[t16][c] = *(const short8*)
            (Kg + base_bh + (size_t)(kt * 64 + t16 * 16 + lr) * DIM + c * 32 + lg * 8);
    // V fragments (issue early; latency hides under QK + softmax)
    short8 vf[4][2];
#pragma unroll
    for (int d = 0; d < 4; ++d)
#pragma unroll
      for (int c = 0; c < 2; ++c)
        vf[d][c] = *(const short8*)
            (Vt + vt_bh + (size_t)(d * 16 + lr) * NSEQ + kt * 64 + c * 32 + lg * 8);

    // QK^T: S^T subtiles (rows=key, col=q)
    f32x4 s[4] = {};
#pragma unroll
    for (int t16 = 0; t16 < 4; ++t16)
#pragma unroll
      for (int c = 0; c < 2; ++c)
        s[t16] = __builtin_amdgcn_mfma_f32_16x16x32_bf16(
            kf[t16][c], qf[c], s[t16], 0, 0, 0);

    // mask (diagonal tile only) + online softmax (lane-local q)
    const bool diag = (kt == qt);
    float mloc = -1e30f;
#pragma unroll
    for (int t16 = 0; t16 < 4; ++t16)
#pragma unroll
      for (int j = 0; j < 4; ++j) {
        float v = s[t16][j];
        if (diag && (kt * 64 + t16 * 16 + lg * 4 + j) > qg) v = -1e30f;
        s[t16][j] = v;
        mloc = fmaxf(mloc, v);
      }
    mloc = fmaxf(mloc, __shfl_xor(mloc, 16));
    mloc = fmaxf(mloc, __shfl_xor(mloc, 32));
    const float m_new = fmaxf(m_run, mloc);
    const float a = exp2f((m_run - m_new) * EXP_SCALE);
    float psum = 0.f;
    u16x4 pk[4];
#pragma unroll
    for (int t16 = 0; t16 < 4; ++t16)
#pragma unroll
      for (int j = 0; j < 4; ++j) {
        const float p = exp2f((s[t16][j] - m_new) * EXP_SCALE);
        psum += p;
        pk[t16][j] = f2bf(p);
      }
    psum += __shfl_xor(psum, 16);
    psum += __shfl_xor(psum, 32);
    l_run = l_run * a + psum;
    m_run = m_new;
#pragma unroll
    for (int d = 0; d < 4; ++d) acc_o[d] *= a;

    // P -> wave-private LDS (swizzled), then PV
#pragma unroll
    for (int t16 = 0; t16 < 4; ++t16)
      *(u16x4*)(pbase + lr * 128 + ((t16 * 32 + lg * 8) ^ psw)) = pk[t16];

#pragma unroll
    for (int c = 0; c < 2; ++c) {
      const short8 pf = *(const short8*)
          (pbase + lr * 128 + ((c * 64 + lg * 16) ^ psw));
#pragma unroll
      for (int d = 0; d < 4; ++d)
        acc_o[d] = __builtin_amdgcn_mfma_f32_16x16x32_bf16(
            vf[d][c], pf, acc_o[d], 0, 0, 0);
    }
  }

  // write partial: O^T frag col=q(lr), row dh=d*16+lg*4+j
  float* slot = Part + (((size_t)(b * NHEAD + h) * 16 + qt) * 4 + cc) * SLOT;
  const int ql = w * 16 + lr;
#pragma unroll
  for (int d = 0; d < 4; ++d)
    *(f32x4*)(slot + ql * 64 + d * 16 + lg * 4) = acc_o[d];
  if (lg == 0) {
    slot[4096 + ql] = m_run;
    slot[4160 + ql] = l_run;
  }
}

// ---------------------------------------------------------------------------
// Merge split-K partials -> bf16 attention output.
// Block = (qt, h, b); thread t: q = t>>2, dh segment = (t&3)*16.
// ---------------------------------------------------------------------------
__global__ __launch_bounds__(256) void attn_merge(
    const float* __restrict__ Part, u16* __restrict__ AOb) {
  const int qt = blockIdx.x, h = blockIdx.y, b = blockIdx.z;
  const int t = threadIdx.x;
  const int q = t >> 2, quad = t & 3;
  const int nc = (qt >> 2) + 1;
  const float* base = Part + ((size_t)(b * NHEAD + h) * 16 + qt) * 4 * SLOT;

  float mv[4], lv[4];
  float M = -1e30f;
  for (int c = 0; c < nc; ++c) {
    mv[c] = base[c * SLOT + 4096 + q];
    lv[c] = base[c * SLOT + 4160 + q];
    M = fmaxf(M, mv[c]);
  }
  float L = 0.f, fc[4];
  for (int c = 0; c < nc; ++c) {
    fc[c] = exp2f((mv[c] - M) * EXP_SCALE);
    L += lv[c] * fc[c];
  }
  const float inv = 1.f / L;

  float o[16] = {};
  for (int c = 0; c < nc; ++c) {
    const float* op = base + c * SLOT + q * 64 + quad * 16;
    const float f = fc[c];
#pragma unroll
    for (int i = 0; i < 4; ++i) {
      const f32x4 v = *(const f32x4*)(op + i * 4);
      o[i * 4 + 0] += f * v[0]; o[i * 4 + 1] += f * v[1];
      o[i * 4 + 2] += f * v[2]; o[i * 4 + 3] += f * v[3];
    }
  }

  u16* dst = AOb + (size_t)(b * NSEQ + qt * 64 + q) * DIM + h * DH + quad * 16;
  u16x8 o0, o1;
#pragma unroll
  for (int i = 0; i < 8; ++i) { o0[i] = f2bf(o[i] * inv); o1[i] = f2bf(o[8 + i] * inv); }
  *(u16x8*)(dst)     = o0;
  *(u16x8*)(dst + 8) = o1;
}

// ---------------------------------------------------------------------------
extern "C" void kernel_launch(void* const* d_in, const int* in_sizes, int n_in,
                              void* d_out, int out_size, void* d_ws, size_t ws_size,
                              hipStream_t stream) {
  const float* x  = (const float*)d_in[0];
  // d_in[1] = causal mask (ignored; mask is m > n analytically)
  const float* wq = (const float*)d_in[2];
  const float* bq = (const float*)d_in[3];
  const float* wk = (const float*)d_in[4];
  const float* bk = (const float*)d_in[5];
  const float* wv = (const float*)d_in[6];
  const float* bv = (const float*)d_in[7];
  const float* wo = (const float*)d_in[8];
  const float* bo = (const float*)d_in[9];

  char* ws = (char*)d_ws;
  u16* Wd    = (u16*)(ws);                       //  0..8MB  4 dense bf16 W
  u16* Xb    = (u16*)(ws + ((size_t)8  << 20));  //  8..12MB x bf16
  u16* Qb    = (u16*)(ws + ((size_t)12 << 20));  // 12..16MB Q bf16
  u16* Kb    = (u16*)(ws + ((size_t)16 << 20));  // 16..20MB K bf16
  u16* Vb    = (u16*)(ws + ((size_t)20 << 20));  // 20..24MB V bf16
  u16* Vt    = (u16*)(ws + ((size_t)24 << 20));  // 24..28MB V^T bf16
  u16* AOb   = (u16*)(ws + ((size_t)28 << 20));  // 28..32MB attn out bf16
  float* Prt = (float*)(ws + ((size_t)32 << 20)); // 32..68MB split-K partials

  // 1) densify circulant weights to dense bf16
  densify_bf16<<<dim3(512, 1, 4), 256, 0, stream>>>(wq, wk, wv, wo, Wd);

  // 2) x -> bf16
  cvt_bf16<<<dim3((BATCH * NSEQ * DIM) / (256 * 8), 1, 1), 256, 0, stream>>>(x, Xb);

  // 3) Q/K/V projections (bf16 MFMA, bf16 out)
  gemm_bf16_nt<1><<<dim3(DIM / 128, (BATCH * NSEQ) / 128, 3), 256, 0, stream>>>(
      Xb, Wd, bq, bk, bv, Qb, Kb, Vb);

  // 4) V -> V^T per (b,h)
  transpose_v<<<dim3(NSEQ / 256, NHEAD, BATCH), 256, 0, stream>>>(Vb, Vt);

  // 5) split-K causal attention: 40 (qt,chunk) pairs per (b,h)
  attn_split<<<dim3(40, NHEAD, BATCH), 256, 0, stream>>>(Qb, Kb, Vt, Prt);

  // 6) merge partials -> bf16
  attn_merge<<<dim3(16, NHEAD, BATCH), 256, 0, stream>>>(Prt, AOb);

  // 7) output projection (fp32 out)
  gemm_bf16_nt<0><<<dim3(DIM / 128, (BATCH * NSEQ) / 128, 1), 256, 0, stream>>>(
      AOb, Wd + (size_t)3 * DIM * DIM, bo, bo, bo, d_out, d_out, d_out);
}

// Round 7
// 88.319 us; speedup vs baseline: 1.3017x; 1.2709x over previous
//
#include <hip/hip_runtime.h>
#include <hip/hip_bf16.h>

#define DIM   1024
#define NSEQ  1024
#define BATCH 2
#define NHEAD 16
#define DH    64

typedef unsigned short u16;
typedef __attribute__((ext_vector_type(8))) short  short8;
typedef __attribute__((ext_vector_type(4))) float  f32x4;
typedef __attribute__((ext_vector_type(8))) unsigned short u16x8;
typedef __attribute__((ext_vector_type(4))) unsigned short u16x4;

// log2(e) / sqrt(DH)
#define EXP_SCALE 0.18033688011112042f
// partial slot: 64x64 O (4096) + m (64) + l (64), padded
#define SLOT 4352

__device__ __forceinline__ u16 f2bf(float f) {
  union { float f; unsigned u; } v; v.f = f;
  unsigned r = v.u + 0x7FFFu + ((v.u >> 16) & 1u);   // RNE
  return (u16)(r >> 16);
}

#define GLD(src, dst)                                                          \
  __builtin_amdgcn_global_load_lds(                                           \
      (const __attribute__((address_space(1))) void*)(src),                   \
      (__attribute__((address_space(3))) void*)(dst), 16, 0, 0)

// ---------------------------------------------------------------------------
// Densify block-circulant weights -> bf16 dense, 8 cols/thread.
// ---------------------------------------------------------------------------
__global__ __launch_bounds__(256) void densify_bf16(
    const float* __restrict__ wq, const float* __restrict__ wk,
    const float* __restrict__ wv, const float* __restrict__ wo,
    u16* __restrict__ Wd) {
  const int z = blockIdx.z;
  const float* w = (z == 0) ? wq : (z == 1) ? wk : (z == 2) ? wv : wo;
  u16* out = Wd + (size_t)z * DIM * DIM;
  const int idx8 = blockIdx.x * 256 + threadIdx.x;
  const int r  = idx8 >> 7;
  const int q  = idx8 & 127;
  const int p  = r >> 3, a = r & 7;
  const float* wrow = w + (size_t)(p * 128 + q) * 8;
  const float4 w0 = *(const float4*)(wrow);
  const float4 w1 = *(const float4*)(wrow + 4);
  const float wv8[8] = {w0.x, w0.y, w0.z, w0.w, w1.x, w1.y, w1.z, w1.w};
  u16x8 o;
#pragma unroll
  for (int j = 0; j < 8; ++j) o[j] = f2bf(wv8[(a - j) & 7]);
  ((u16x8*)out)[idx8] = o;
}

// ---------------------------------------------------------------------------
// fp32 -> bf16 conversion, 8 elements/thread
// ---------------------------------------------------------------------------
__global__ __launch_bounds__(256) void cvt_bf16(
    const float* __restrict__ in, u16* __restrict__ out) {
  const int i = blockIdx.x * 256 + threadIdx.x;
  const float4 a = ((const float4*)in)[2 * i];
  const float4 b = ((const float4*)in)[2 * i + 1];
  u16x8 o;
  o[0] = f2bf(a.x); o[1] = f2bf(a.y); o[2] = f2bf(a.z); o[3] = f2bf(a.w);
  o[4] = f2bf(b.x); o[5] = f2bf(b.y); o[6] = f2bf(b.z); o[7] = f2bf(b.w);
  ((u16x8*)out)[i] = o;
}

// ---------------------------------------------------------------------------
// bf16 MFMA GEMM (NT) + bias, templated tile, 2-phase double-buffered.
// C[m][n] = sum_k A[m][k]*W[n][k] + bias[n].  256 thr = 4 waves (2x2).
// ---------------------------------------------------------------------------
template <int BM, int BN, int BFOUT>
__global__ __launch_bounds__(256) void gemm_bf16_nt(
    const u16* __restrict__ A, const u16* __restrict__ Wbase,
    const float* __restrict__ b0, const float* __restrict__ b1,
    const float* __restrict__ b2,
    void* __restrict__ C0, void* __restrict__ C1, void* __restrict__ C2) {
  constexpr int MR = BM / 32, NR = BN / 32;      // frags per wave (2x2 waves)
  constexpr int CA = BM / 64, CB = BN / 64;      // staging chunks per wave

  const int z = blockIdx.z;
  const u16* W      = Wbase + (size_t)z * DIM * DIM;
  const float* bias = (z == 0) ? b0 : (z == 1) ? b1 : b2;
  void* C           = (z == 0) ? C0 : (z == 1) ? C1 : C2;

  __shared__ u16 As[2][BM * 32];
  __shared__ u16 Bs[2][BN * 32];

  const int tid  = threadIdx.x;
  const int w    = tid >> 6, lane = tid & 63;
  const int mb   = blockIdx.y * BM, nb = blockIdx.x * BN;

  f32x4 acc[MR][NR] = {};

  const int m0 = (w >> 1) * (BM / 2), n0 = (w & 1) * (BN / 2);
  const int lr = lane & 15, lk = (lane >> 4) * 8;

  // staging lane mapping: chunk cb, lane l -> row cb*16 + l/4, kcol (l&3)*8
  const int srow = lane >> 2, skc = (lane & 3) * 8;

#define STAGE(buf, k0)                                                         \
  do {                                                                         \
    _Pragma("unroll")                                                          \
    for (int i = 0; i < CA; ++i) {                                             \
      const int cb = w * CA + i;                                               \
      GLD(A + (size_t)(mb + cb * 16 + srow) * DIM + (k0) + skc,                \
          As[buf] + cb * 512);                                                 \
    }                                                                          \
    _Pragma("unroll")                                                          \
    for (int i = 0; i < CB; ++i) {                                             \
      const int cb = w * CB + i;                                               \
      GLD(W + (size_t)(nb + cb * 16 + srow) * DIM + (k0) + skc,                \
          Bs[buf] + cb * 512);                                                 \
    }                                                                          \
  } while (0)

  STAGE(0, 0);
  __syncthreads();
  int cur = 0;
  for (int k0 = 0; k0 < DIM; k0 += 32) {
    if (k0 + 32 < DIM) STAGE(cur ^ 1, k0 + 32);

    short8 a[MR], b[NR];
#pragma unroll
    for (int mi = 0; mi < MR; ++mi)
      a[mi] = *(const short8*)&As[cur][(m0 + mi * 16 + lr) * 32 + lk];
#pragma unroll
    for (int ni = 0; ni < NR; ++ni)
      b[ni] = *(const short8*)&Bs[cur][(n0 + ni * 16 + lr) * 32 + lk];
#pragma unroll
    for (int mi = 0; mi < MR; ++mi)
#pragma unroll
      for (int ni = 0; ni < NR; ++ni)
        acc[mi][ni] = __builtin_amdgcn_mfma_f32_16x16x32_bf16(
            a[mi], b[ni], acc[mi][ni], 0, 0, 0);

    __syncthreads();
    cur ^= 1;
  }
#undef STAGE

  // epilogue: C/D layout col = lane&15, row = (lane>>4)*4 + j
  const int col = lane & 15, rq = (lane >> 4) * 4;
#pragma unroll
  for (int ni = 0; ni < NR; ++ni) {
    const int gc = nb + n0 + ni * 16 + col;
    const float bv = bias[gc];
#pragma unroll
    for (int mi = 0; mi < MR; ++mi) {
      const size_t rbase = (size_t)(mb + m0 + mi * 16 + rq) * DIM + gc;
#pragma unroll
      for (int j = 0; j < 4; ++j) {
        const float v = acc[mi][ni][j] + bv;
        if (BFOUT) ((u16*)C)[rbase + (size_t)j * DIM] = f2bf(v);
        else       ((float*)C)[rbase + (size_t)j * DIM] = v;
      }
    }
  }
}

// ---------------------------------------------------------------------------
// V transpose: Vb [b][n][DIM] (head slice) -> Vt [b][h][dh=64][NSEQ].
// ---------------------------------------------------------------------------
__global__ __launch_bounds__(256) void transpose_v(
    const u16* __restrict__ Vb, u16* __restrict__ Vt) {
  const int n0 = blockIdx.x * 256;
  const int h  = blockIdx.y;
  const int b  = blockIdx.z;
  const int tid = threadIdx.x;
  const int dhb = tid & 7;
  const int nb8 = tid >> 3;

  const u16* src = Vb + ((size_t)(b * NSEQ) + n0 + nb8 * 8) * DIM + h * DH + dhb * 8;
  u16x8 v[8];
#pragma unroll
  for (int i = 0; i < 8; ++i) v[i] = *(const u16x8*)(src + (size_t)i * DIM);

  u16* dst = Vt + ((size_t)(b * NHEAD + h) * DH + dhb * 8) * NSEQ + n0 + nb8 * 8;
#pragma unroll
  for (int j = 0; j < 8; ++j) {
    u16x8 o;
#pragma unroll
    for (int i = 0; i < 8; ++i) o[i] = v[i][j];
    *(u16x8*)(dst + (size_t)j * NSEQ) = o;
  }
}

// ---------------------------------------------------------------------------
// Split-K causal flash attention, LDS-staged + double-buffered.
// Block = (qt, chunk of <=4 KV tiles) x (h, b); 4 waves x 16 q.
// K and V^T staged via global_load_lds with pre-swizzled global sources;
// STAGE(next) issued before compute(cur), one __syncthreads per tile.
// Swapped QK^T -> lane-local softmax; PV via V^T frags + P in wave LDS.
// Writes f32 partial O[64][64] + m[64] + l[64] per block.
// ---------------------------------------------------------------------------
__global__ __launch_bounds__(256, 4) void attn_split(
    const u16* __restrict__ Qg, const u16* __restrict__ Kg,
    const u16* __restrict__ Vt, float* __restrict__ Part) {
  // blockIdx.x -> (qt, cc), heavy qt first
  int idx = blockIdx.x, qt = 0, cc = 0;
  for (int t = 15; t >= 0; --t) {
    const int nc = (t >> 2) + 1;
    if (idx < nc) { qt = t; cc = idx; break; }
    idx -= nc;
  }
  const int h = blockIdx.y, b = blockIdx.z;
  const int tid = threadIdx.x;
  const int w  = tid >> 6, l = tid & 63;
  const int lr = l & 15, lg = l >> 4;

  __shared__ u16 Klds[2][64 * 64];     // [key][dh], xor-swizzled (16B granule)
  __shared__ u16 Vlds[2][64 * 64];     // [dh][key], xor-swizzled
  __shared__ u16 Plds[4][16 * 64];     // per-wave P [q][key], swizzled

  const int qg = qt * 64 + w * 16 + lr;
  const size_t base_bh = (size_t)b * NSEQ * DIM + (size_t)h * DH;
  const size_t vt_bh   = (size_t)(b * NHEAD + h) * DH * NSEQ;

  short8 qf[2];
#pragma unroll
  for (int c = 0; c < 2; ++c)
    qf[c] = *(const short8*)(Qg + base_bh + (size_t)qg * DIM + c * 32 + lg * 8);

  f32x4 acc_o[4] = {};
  float m_run = -1e30f, l_run = 0.f;
  char* pbase = (char*)Plds[w];
  const int psw = (lr & 7) << 4;

  // staging lane mapping (per chunk-block cb): row = cb*8 + l/8,
  // 16B slot j = l&7 holds global col16 = j ^ (row&7)  (inverse-swizzle src)
  const int srow8 = l >> 3;
  const int sj    = l & 7;

#define ASTAGE(buf, kt)                                                        \
  do {                                                                         \
    _Pragma("unroll")                                                          \
    for (int i = 0; i < 2; ++i) {                                              \
      const int cb  = w * 2 + i;                                               \
      const int row = cb * 8 + srow8;                                          \
      const int c16 = sj ^ (row & 7);                                          \
      GLD(Kg + base_bh + (size_t)((kt) * 64 + row) * DIM + c16 * 8,            \
          Klds[buf] + cb * 512);                                               \
      GLD(Vt + vt_bh + (size_t)row * NSEQ + (kt) * 64 + c16 * 8,               \
          Vlds[buf] + cb * 512);                                               \
    }                                                                          \
  } while (0)

  const int kt0 = cc * 4;
  const int kt_end = min(kt0 + 4, qt + 1);

  ASTAGE(0, kt0);
  __syncthreads();
  int cur = 0;

  for (int kt = kt0; kt < kt_end; ++kt) {
    if (kt + 1 < kt_end) ASTAGE(cur ^ 1, kt + 1);

    // --- QK^T: S^T subtiles (rows=key, col=q) from swizzled Klds ---
    f32x4 s[4] = {};
#pragma unroll
    for (int t16 = 0; t16 < 4; ++t16) {
      const int row = t16 * 16 + lr;
#pragma unroll
      for (int c = 0; c < 2; ++c) {
        const int c16 = (c * 4 + lg) ^ (row & 7);
        const short8 kf = *(const short8*)
            ((const char*)Klds[cur] + row * 128 + c16 * 16);
        s[t16] = __builtin_amdgcn_mfma_f32_16x16x32_bf16(kf, qf[c], s[t16], 0, 0, 0);
      }
    }

    // --- mask (diagonal tile only) + online softmax (lane-local q) ---
    const bool diag = (kt == qt);
    float mloc = -1e30f;
#pragma unroll
    for (int t16 = 0; t16 < 4; ++t16)
#pragma unroll
      for (int j = 0; j < 4; ++j) {
        float v = s[t16][j];
        if (diag && (kt * 64 + t16 * 16 + lg * 4 + j) > qg) v = -1e30f;
        s[t16][j] = v;
        mloc = fmaxf(mloc, v);
      }
    mloc = fmaxf(mloc, __shfl_xor(mloc, 16));
    mloc = fmaxf(mloc, __shfl_xor(mloc, 32));
    const float m_new = fmaxf(m_run, mloc);
    const float a = exp2f((m_run - m_new) * EXP_SCALE);
    float psum = 0.f;
    u16x4 pk[4];
#pragma unroll
    for (int t16 = 0; t16 < 4; ++t16)
#pragma unroll
      for (int j = 0; j < 4; ++j) {
        const float p = exp2f((s[t16][j] - m_new) * EXP_SCALE);
        psum += p;
        pk[t16][j] = f2bf(p);
      }
    psum += __shfl_xor(psum, 16);
    psum += __shfl_xor(psum, 32);
    l_run = l_run * a + psum;
    m_run = m_new;
#pragma unroll
    for (int d = 0; d < 4; ++d) acc_o[d] *= a;

    // --- P -> wave-private LDS (swizzled), then PV from swizzled Vlds ---
#pragma unroll
    for (int t16 = 0; t16 < 4; ++t16)
      *(u16x4*)(pbase + lr * 128 + ((t16 * 32 + lg * 8) ^ psw)) = pk[t16];

#pragma unroll
    for (int c = 0; c < 2; ++c) {
      const short8 pf = *(const short8*)
          (pbase + lr * 128 + ((c * 64 + lg * 16) ^ psw));
#pragma unroll
      for (int d = 0; d < 4; ++d) {
        const int dh = d * 16 + lr;
        const int c16 = (c * 4 + lg) ^ (dh & 7);
        const short8 vf = *(const short8*)
            ((const char*)Vlds[cur] + dh * 128 + c16 * 16);
        acc_o[d] = __builtin_amdgcn_mfma_f32_16x16x32_bf16(vf, pf, acc_o[d], 0, 0, 0);
      }
    }

    __syncthreads();     // next-tile stage resident; cur reads complete
    cur ^= 1;
  }
#undef ASTAGE

  // write partial: O^T frag col=q(lr), row dh=d*16+lg*4+j
  float* slot = Part + (((size_t)(b * NHEAD + h) * 16 + qt) * 4 + cc) * SLOT;
  const int ql = w * 16 + lr;
#pragma unroll
  for (int d = 0; d < 4; ++d)
    *(f32x4*)(slot + ql * 64 + d * 16 + lg * 4) = acc_o[d];
  if (lg == 0) {
    slot[4096 + ql] = m_run;
    slot[4160 + ql] = l_run;
  }
}

// ---------------------------------------------------------------------------
// Merge split-K partials -> bf16 attention output.
// ---------------------------------------------------------------------------
__global__ __launch_bounds__(256) void attn_merge(
    const float* __restrict__ Part, u16* __restrict__ AOb) {
  const int qt = blockIdx.x, h = blockIdx.y, b = blockIdx.z;
  const int t = threadIdx.x;
  const int q = t >> 2, quad = t & 3;
  const int nc = (qt >> 2) + 1;
  const float* base = Part + ((size_t)(b * NHEAD + h) * 16 + qt) * 4 * SLOT;

  float mv[4], lv[4];
  float M = -1e30f;
  for (int c = 0; c < nc; ++c) {
    mv[c] = base[c * SLOT + 4096 + q];
    lv[c] = base[c * SLOT + 4160 + q];
    M = fmaxf(M, mv[c]);
  }
  float L = 0.f, fc[4];
  for (int c = 0; c < nc; ++c) {
    fc[c] = exp2f((mv[c] - M) * EXP_SCALE);
    L += lv[c] * fc[c];
  }
  const float inv = 1.f / L;

  float o[16] = {};
  for (int c = 0; c < nc; ++c) {
    const float* op = base + c * SLOT + q * 64 + quad * 16;
    const float f = fc[c];
#pragma unroll
    for (int i = 0; i < 4; ++i) {
      const f32x4 v = *(const f32x4*)(op + i * 4);
      o[i * 4 + 0] += f * v[0]; o[i * 4 + 1] += f * v[1];
      o[i * 4 + 2] += f * v[2]; o[i * 4 + 3] += f * v[3];
    }
  }

  u16* dst = AOb + (size_t)(b * NSEQ + qt * 64 + q) * DIM + h * DH + quad * 16;
  u16x8 o0, o1;
#pragma unroll
  for (int i = 0; i < 8; ++i) { o0[i] = f2bf(o[i] * inv); o1[i] = f2bf(o[8 + i] * inv); }
  *(u16x8*)(dst)     = o0;
  *(u16x8*)(dst + 8) = o1;
}

// ---------------------------------------------------------------------------
extern "C" void kernel_launch(void* const* d_in, const int* in_sizes, int n_in,
                              void* d_out, int out_size, void* d_ws, size_t ws_size,
                              hipStream_t stream) {
  const float* x  = (const float*)d_in[0];
  // d_in[1] = causal mask (ignored; mask is m > n analytically)
  const float* wq = (const float*)d_in[2];
  const float* bq = (const float*)d_in[3];
  const float* wk = (const float*)d_in[4];
  const float* bk = (const float*)d_in[5];
  const float* wv = (const float*)d_in[6];
  const float* bv = (const float*)d_in[7];
  const float* wo = (const float*)d_in[8];
  const float* bo = (const float*)d_in[9];

  char* ws = (char*)d_ws;
  u16* Wd    = (u16*)(ws);                        //  0..8MB  4 dense bf16 W
  u16* Xb    = (u16*)(ws + ((size_t)8  << 20));   //  8..12MB x bf16
  u16* Qb    = (u16*)(ws + ((size_t)12 << 20));   // 12..16MB Q bf16
  u16* Kb    = (u16*)(ws + ((size_t)16 << 20));   // 16..20MB K bf16
  u16* Vb    = (u16*)(ws + ((size_t)20 << 20));   // 20..24MB V bf16
  u16* Vt    = (u16*)(ws + ((size_t)24 << 20));   // 24..28MB V^T bf16
  u16* AOb   = (u16*)(ws + ((size_t)28 << 20));   // 28..32MB attn out bf16
  float* Prt = (float*)(ws + ((size_t)32 << 20)); // 32..68MB split-K partials

  // 1) densify circulant weights to dense bf16
  densify_bf16<<<dim3(512, 1, 4), 256, 0, stream>>>(wq, wk, wv, wo, Wd);

  // 2) x -> bf16
  cvt_bf16<<<dim3((BATCH * NSEQ * DIM) / (256 * 8), 1, 1), 256, 0, stream>>>(x, Xb);

  // 3) Q/K/V projections: BM=128, BN=64 -> 768 blocks (3/CU)
  gemm_bf16_nt<128, 64, 1><<<dim3(DIM / 64, (BATCH * NSEQ) / 128, 3), 256, 0, stream>>>(
      Xb, Wd, bq, bk, bv, Qb, Kb, Vb);

  // 4) V -> V^T per (b,h)
  transpose_v<<<dim3(NSEQ / 256, NHEAD, BATCH), 256, 0, stream>>>(Vb, Vt);

  // 5) split-K causal attention: 40 (qt,chunk) pairs per (b,h), LDS dbuf
  attn_split<<<dim3(40, NHEAD, BATCH), 256, 0, stream>>>(Qb, Kb, Vt, Prt);

  // 6) merge partials -> bf16
  attn_merge<<<dim3(16, NHEAD, BATCH), 256, 0, stream>>>(Prt, AOb);

  // 7) output projection: BM=64, BN=64 -> 512 blocks (2/CU)
  gemm_bf16_nt<64, 64, 0><<<dim3(DIM / 64, (BATCH * NSEQ) / 64, 1), 256, 0, stream>>>(
      AOb, Wd + (size_t)3 * DIM * DIM, bo, bo, bo, d_out, d_out, d_out);
}

// Round 8
// 86.130 us; speedup vs baseline: 1.3348x; 1.0254x over previous
//
#include <hip/hip_runtime.h>
#include <hip/hip_bf16.h>

#define DIM   1024
#define NSEQ  1024
#define BATCH 2
#define NHEAD 16
#define DH    64

typedef unsigned short u16;
typedef __attribute__((ext_vector_type(8))) short  short8;
typedef __attribute__((ext_vector_type(4))) float  f32x4;
typedef __attribute__((ext_vector_type(8))) unsigned short u16x8;
typedef __attribute__((ext_vector_type(4))) unsigned short u16x4;

// log2(e) / sqrt(DH)
#define EXP_SCALE 0.18033688011112042f
// partial slot: 64x64 O (4096) + m (64) + l (64), padded
#define SLOT 4352

__device__ __forceinline__ u16 f2bf(float f) {
  union { float f; unsigned u; } v; v.f = f;
  unsigned r = v.u + 0x7FFFu + ((v.u >> 16) & 1u);   // RNE
  return (u16)(r >> 16);
}

#define GLD(src, dst)                                                          \
  __builtin_amdgcn_global_load_lds(                                           \
      (const __attribute__((address_space(1))) void*)(src),                   \
      (__attribute__((address_space(3))) void*)(dst), 16, 0, 0)

// ---------------------------------------------------------------------------
// Fused prep: densify circulant weights -> bf16 dense (blocks 0..2047),
// x fp32 -> bf16 (blocks 2048..3071).
// ---------------------------------------------------------------------------
__global__ __launch_bounds__(256) void prep_bf16(
    const float* __restrict__ wq, const float* __restrict__ wk,
    const float* __restrict__ wv, const float* __restrict__ wo,
    const float* __restrict__ x,
    u16* __restrict__ Wd, u16* __restrict__ Xb) {
  const int bid = blockIdx.x;
  if (bid < 2048) {
    const int z = bid >> 9;
    const float* w = (z == 0) ? wq : (z == 1) ? wk : (z == 2) ? wv : wo;
    u16* out = Wd + (size_t)z * DIM * DIM;
    const int idx8 = (bid & 511) * 256 + threadIdx.x;
    const int r = idx8 >> 7;
    const int q = idx8 & 127;
    const int p = r >> 3, a = r & 7;
    const float* wrow = w + (size_t)(p * 128 + q) * 8;
    const float4 w0 = *(const float4*)(wrow);
    const float4 w1 = *(const float4*)(wrow + 4);
    const float wv8[8] = {w0.x, w0.y, w0.z, w0.w, w1.x, w1.y, w1.z, w1.w};
    u16x8 o;
#pragma unroll
    for (int j = 0; j < 8; ++j) o[j] = f2bf(wv8[(a - j) & 7]);
    ((u16x8*)out)[idx8] = o;
  } else {
    const int i = (bid - 2048) * 256 + threadIdx.x;
    const float4 a = ((const float4*)x)[2 * i];
    const float4 b = ((const float4*)x)[2 * i + 1];
    u16x8 o;
    o[0] = f2bf(a.x); o[1] = f2bf(a.y); o[2] = f2bf(a.z); o[3] = f2bf(a.w);
    o[4] = f2bf(b.x); o[5] = f2bf(b.y); o[6] = f2bf(b.z); o[7] = f2bf(b.w);
    ((u16x8*)Xb)[i] = o;
  }
}

// ---------------------------------------------------------------------------
// bf16 MFMA GEMM (NT) + bias, templated tile, 2-phase double-buffered.
// C[m][n] = sum_k A[m][k]*W[n][k] + bias[n].  256 thr = 4 waves (2x2).
// ---------------------------------------------------------------------------
template <int BM, int BN, int BFOUT>
__global__ __launch_bounds__(256) void gemm_bf16_nt(
    const u16* __restrict__ A, const u16* __restrict__ Wbase,
    const float* __restrict__ b0, const float* __restrict__ b1,
    const float* __restrict__ b2,
    void* __restrict__ C0, void* __restrict__ C1, void* __restrict__ C2) {
  constexpr int MR = BM / 32, NR = BN / 32;      // frags per wave (2x2 waves)
  constexpr int CA = BM / 64, CB = BN / 64;      // staging chunks per wave

  const int z = blockIdx.z;
  const u16* W      = Wbase + (size_t)z * DIM * DIM;
  const float* bias = (z == 0) ? b0 : (z == 1) ? b1 : b2;
  void* C           = (z == 0) ? C0 : (z == 1) ? C1 : C2;

  __shared__ u16 As[2][BM * 32];
  __shared__ u16 Bs[2][BN * 32];

  const int tid  = threadIdx.x;
  const int w    = tid >> 6, lane = tid & 63;
  const int mb   = blockIdx.y * BM, nb = blockIdx.x * BN;

  f32x4 acc[MR][NR] = {};

  const int m0 = (w >> 1) * (BM / 2), n0 = (w & 1) * (BN / 2);
  const int lr = lane & 15, lk = (lane >> 4) * 8;

  // staging lane mapping: chunk cb, lane l -> row cb*16 + l/4, kcol (l&3)*8
  const int srow = lane >> 2, skc = (lane & 3) * 8;

#define STAGE(buf, k0)                                                         \
  do {                                                                         \
    _Pragma("unroll")                                                          \
    for (int i = 0; i < CA; ++i) {                                             \
      const int cb = w * CA + i;                                               \
      GLD(A + (size_t)(mb + cb * 16 + srow) * DIM + (k0) + skc,                \
          As[buf] + cb * 512);                                                 \
    }                                                                          \
    _Pragma("unroll")                                                          \
    for (int i = 0; i < CB; ++i) {                                             \
      const int cb = w * CB + i;                                               \
      GLD(W + (size_t)(nb + cb * 16 + srow) * DIM + (k0) + skc,                \
          Bs[buf] + cb * 512);                                                 \
    }                                                                          \
  } while (0)

  STAGE(0, 0);
  __syncthreads();
  int cur = 0;
  for (int k0 = 0; k0 < DIM; k0 += 32) {
    if (k0 + 32 < DIM) STAGE(cur ^ 1, k0 + 32);

    short8 a[MR], b[NR];
#pragma unroll
    for (int mi = 0; mi < MR; ++mi)
      a[mi] = *(const short8*)&As[cur][(m0 + mi * 16 + lr) * 32 + lk];
#pragma unroll
    for (int ni = 0; ni < NR; ++ni)
      b[ni] = *(const short8*)&Bs[cur][(n0 + ni * 16 + lr) * 32 + lk];
#pragma unroll
    for (int mi = 0; mi < MR; ++mi)
#pragma unroll
      for (int ni = 0; ni < NR; ++ni)
        acc[mi][ni] = __builtin_amdgcn_mfma_f32_16x16x32_bf16(
            a[mi], b[ni], acc[mi][ni], 0, 0, 0);

    __syncthreads();
    cur ^= 1;
  }
#undef STAGE

  // epilogue: C/D layout col = lane&15, row = (lane>>4)*4 + j
  const int col = lane & 15, rq = (lane >> 4) * 4;
#pragma unroll
  for (int ni = 0; ni < NR; ++ni) {
    const int gc = nb + n0 + ni * 16 + col;
    const float bv = bias[gc];
#pragma unroll
    for (int mi = 0; mi < MR; ++mi) {
      const size_t rbase = (size_t)(mb + m0 + mi * 16 + rq) * DIM + gc;
#pragma unroll
      for (int j = 0; j < 4; ++j) {
        const float v = acc[mi][ni][j] + bv;
        if (BFOUT) ((u16*)C)[rbase + (size_t)j * DIM] = f2bf(v);
        else       ((float*)C)[rbase + (size_t)j * DIM] = v;
      }
    }
  }
}

// ---------------------------------------------------------------------------
// V transpose: Vb [b][n][DIM] (head slice) -> Vt [b][h][dh=64][NSEQ].
// ---------------------------------------------------------------------------
__global__ __launch_bounds__(256) void transpose_v(
    const u16* __restrict__ Vb, u16* __restrict__ Vt) {
  const int n0 = blockIdx.x * 256;
  const int h  = blockIdx.y;
  const int b  = blockIdx.z;
  const int tid = threadIdx.x;
  const int dhb = tid & 7;
  const int nb8 = tid >> 3;

  const u16* src = Vb + ((size_t)(b * NSEQ) + n0 + nb8 * 8) * DIM + h * DH + dhb * 8;
  u16x8 v[8];
#pragma unroll
  for (int i = 0; i < 8; ++i) v[i] = *(const u16x8*)(src + (size_t)i * DIM);

  u16* dst = Vt + ((size_t)(b * NHEAD + h) * DH + dhb * 8) * NSEQ + n0 + nb8 * 8;
#pragma unroll
  for (int j = 0; j < 8; ++j) {
    u16x8 o;
#pragma unroll
    for (int i = 0; i < 8; ++i) o[i] = v[i][j];
    *(u16x8*)(dst + (size_t)j * NSEQ) = o;
  }
}

// ---------------------------------------------------------------------------
// Split-K causal flash attention: stage ALL (<=4) K/V tiles up front via
// global_load_lds, ONE __syncthreads, then a barrier-free inner loop.
// Block = (qt, chunk of <=4 KV tiles) x (h, b); 4 waves x 16 q.
// Swapped QK^T -> lane-local softmax; PV via V^T frags + P in wave LDS.
// nc==1 (qt<4): write bf16 AOb directly.  Else write f32 partial slot.
// ---------------------------------------------------------------------------
__global__ __launch_bounds__(256, 4) void attn_split(
    const u16* __restrict__ Qg, const u16* __restrict__ Kg,
    const u16* __restrict__ Vt, float* __restrict__ Part,
    u16* __restrict__ AOb) {
  // blockIdx.x -> (qt, cc), heavy qt first
  int idx = blockIdx.x, qt = 0, cc = 0;
  for (int t = 15; t >= 0; --t) {
    const int nc = (t >> 2) + 1;
    if (idx < nc) { qt = t; cc = idx; break; }
    idx -= nc;
  }
  const int h = blockIdx.y, b = blockIdx.z;
  const int tid = threadIdx.x;
  const int w  = tid >> 6, l = tid & 63;
  const int lr = l & 15, lg = l >> 4;

  __shared__ u16 Klds[4][64 * 64];     // [key][dh], xor-swizzled (16B granule)
  __shared__ u16 Vlds[4][64 * 64];     // [dh][key], xor-swizzled
  __shared__ u16 Plds[4][16 * 64];     // per-wave P [q][key], swizzled

  const int qg = qt * 64 + w * 16 + lr;
  const size_t base_bh = (size_t)b * NSEQ * DIM + (size_t)h * DH;
  const size_t vt_bh   = (size_t)(b * NHEAD + h) * DH * NSEQ;

  short8 qf[2];
#pragma unroll
  for (int c = 0; c < 2; ++c)
    qf[c] = *(const short8*)(Qg + base_bh + (size_t)qg * DIM + c * 32 + lg * 8);

  f32x4 acc_o[4] = {};
  float m_run = -1e30f, l_run = 0.f;
  char* pbase = (char*)Plds[w];
  const int psw = (lr & 7) << 4;

  // staging lane mapping (per chunk-block cb): row = cb*8 + l/8,
  // 16B slot j = l&7 holds global col16 = j ^ (row&7)  (inverse-swizzle src)
  const int srow8 = l >> 3;
  const int sj    = l & 7;

  const int kt0 = cc * 4;
  const int nt  = min(kt0 + 4, qt + 1) - kt0;    // 1..4 tiles

  // --- stage ALL tiles up front (uniform branches), one barrier ---
#pragma unroll
  for (int t = 0; t < 4; ++t) {
    if (t < nt) {
      const int kt = kt0 + t;
#pragma unroll
      for (int i = 0; i < 2; ++i) {
        const int cb  = w * 2 + i;
        const int row = cb * 8 + srow8;
        const int c16 = sj ^ (row & 7);
        GLD(Kg + base_bh + (size_t)(kt * 64 + row) * DIM + c16 * 8,
            Klds[t] + cb * 512);
        GLD(Vt + vt_bh + (size_t)row * NSEQ + kt * 64 + c16 * 8,
            Vlds[t] + cb * 512);
      }
    }
  }
  __syncthreads();     // all K/V tiles resident; no further barriers

  for (int it = 0; it < nt; ++it) {
    const int kt = kt0 + it;

    // --- QK^T: S^T subtiles (rows=key, col=q) from swizzled Klds ---
    f32x4 s[4] = {};
#pragma unroll
    for (int t16 = 0; t16 < 4; ++t16) {
      const int row = t16 * 16 + lr;
#pragma unroll
      for (int c = 0; c < 2; ++c) {
        const int c16 = (c * 4 + lg) ^ (row & 7);
        const short8 kf = *(const short8*)
            ((const char*)Klds[it] + row * 128 + c16 * 16);
        s[t16] = __builtin_amdgcn_mfma_f32_16x16x32_bf16(kf, qf[c], s[t16], 0, 0, 0);
      }
    }

    // --- mask (diagonal tile only) + online softmax (lane-local q) ---
    const bool diag = (kt == qt);
    float mloc = -1e30f;
#pragma unroll
    for (int t16 = 0; t16 < 4; ++t16)
#pragma unroll
      for (int j = 0; j < 4; ++j) {
        float v = s[t16][j];
        if (diag && (kt * 64 + t16 * 16 + lg * 4 + j) > qg) v = -1e30f;
        s[t16][j] = v;
        mloc = fmaxf(mloc, v);
      }
    mloc = fmaxf(mloc, __shfl_xor(mloc, 16));
    mloc = fmaxf(mloc, __shfl_xor(mloc, 32));
    const float m_new = fmaxf(m_run, mloc);
    const float a = exp2f((m_run - m_new) * EXP_SCALE);
    float psum = 0.f;
    u16x4 pk[4];
#pragma unroll
    for (int t16 = 0; t16 < 4; ++t16)
#pragma unroll
      for (int j = 0; j < 4; ++j) {
        const float p = exp2f((s[t16][j] - m_new) * EXP_SCALE);
        psum += p;
        pk[t16][j] = f2bf(p);
      }
    psum += __shfl_xor(psum, 16);
    psum += __shfl_xor(psum, 32);
    l_run = l_run * a + psum;
    m_run = m_new;
#pragma unroll
    for (int d = 0; d < 4; ++d) acc_o[d] *= a;

    // --- P -> wave-private LDS (swizzled), then PV from swizzled Vlds ---
#pragma unroll
    for (int t16 = 0; t16 < 4; ++t16)
      *(u16x4*)(pbase + lr * 128 + ((t16 * 32 + lg * 8) ^ psw)) = pk[t16];

#pragma unroll
    for (int c = 0; c < 2; ++c) {
      const short8 pf = *(const short8*)
          (pbase + lr * 128 + ((c * 64 + lg * 16) ^ psw));
#pragma unroll
      for (int d = 0; d < 4; ++d) {
        const int dh = d * 16 + lr;
        const int c16 = (c * 4 + lg) ^ (dh & 7);
        const short8 vf = *(const short8*)
            ((const char*)Vlds[it] + dh * 128 + c16 * 16);
        acc_o[d] = __builtin_amdgcn_mfma_f32_16x16x32_bf16(vf, pf, acc_o[d], 0, 0, 0);
      }
    }
  }

  const int ql = w * 16 + lr;
  if (qt < 4) {
    // single-chunk: finalize and write bf16 AOb directly (no merge needed)
    const float inv = 1.f / l_run;
    u16* Op = AOb + (size_t)(b * NSEQ + qt * 64 + ql) * DIM + (size_t)h * DH;
#pragma unroll
    for (int d = 0; d < 4; ++d) {
      u16x4 o;
      o[0] = f2bf(acc_o[d][0] * inv); o[1] = f2bf(acc_o[d][1] * inv);
      o[2] = f2bf(acc_o[d][2] * inv); o[3] = f2bf(acc_o[d][3] * inv);
      *(u16x4*)(Op + d * 16 + lg * 4) = o;
    }
  } else {
    // write f32 partial: O^T frag col=q(lr), row dh=d*16+lg*4+j
    float* slot = Part + (((size_t)(b * NHEAD + h) * 16 + qt) * 4 + cc) * SLOT;
#pragma unroll
    for (int d = 0; d < 4; ++d)
      *(f32x4*)(slot + ql * 64 + d * 16 + lg * 4) = acc_o[d];
    if (lg == 0) {
      slot[4096 + ql] = m_run;
      slot[4160 + ql] = l_run;
    }
  }
}

// ---------------------------------------------------------------------------
// Merge split-K partials -> bf16 attention output (qt >= 4 only).
// ---------------------------------------------------------------------------
__global__ __launch_bounds__(256) void attn_merge(
    const float* __restrict__ Part, u16* __restrict__ AOb) {
  const int qt = blockIdx.x + 4, h = blockIdx.y, b = blockIdx.z;
  const int t = threadIdx.x;
  const int q = t >> 2, quad = t & 3;
  const int nc = (qt >> 2) + 1;
  const float* base = Part + ((size_t)(b * NHEAD + h) * 16 + qt) * 4 * SLOT;

  float mv[4], lv[4];
  float M = -1e30f;
  for (int c = 0; c < nc; ++c) {
    mv[c] = base[c * SLOT + 4096 + q];
    lv[c] = base[c * SLOT + 4160 + q];
    M = fmaxf(M, mv[c]);
  }
  float L = 0.f, fc[4];
  for (int c = 0; c < nc; ++c) {
    fc[c] = exp2f((mv[c] - M) * EXP_SCALE);
    L += lv[c] * fc[c];
  }
  const float inv = 1.f / L;

  float o[16] = {};
  for (int c = 0; c < nc; ++c) {
    const float* op = base + c * SLOT + q * 64 + quad * 16;
    const float f = fc[c];
#pragma unroll
    for (int i = 0; i < 4; ++i) {
      const f32x4 v = *(const f32x4*)(op + i * 4);
      o[i * 4 + 0] += f * v[0]; o[i * 4 + 1] += f * v[1];
      o[i * 4 + 2] += f * v[2]; o[i * 4 + 3] += f * v[3];
    }
  }

  u16* dst = AOb + (size_t)(b * NSEQ + qt * 64 + q) * DIM + h * DH + quad * 16;
  u16x8 o0, o1;
#pragma unroll
  for (int i = 0; i < 8; ++i) { o0[i] = f2bf(o[i] * inv); o1[i] = f2bf(o[8 + i] * inv); }
  *(u16x8*)(dst)     = o0;
  *(u16x8*)(dst + 8) = o1;
}

// ---------------------------------------------------------------------------
extern "C" void kernel_launch(void* const* d_in, const int* in_sizes, int n_in,
                              void* d_out, int out_size, void* d_ws, size_t ws_size,
                              hipStream_t stream) {
  const float* x  = (const float*)d_in[0];
  // d_in[1] = causal mask (ignored; mask is m > n analytically)
  const float* wq = (const float*)d_in[2];
  const float* bq = (const float*)d_in[3];
  const float* wk = (const float*)d_in[4];
  const float* bk = (const float*)d_in[5];
  const float* wv = (const float*)d_in[6];
  const float* bv = (const float*)d_in[7];
  const float* wo = (const float*)d_in[8];
  const float* bo = (const float*)d_in[9];

  char* ws = (char*)d_ws;
  u16* Wd    = (u16*)(ws);                        //  0..8MB  4 dense bf16 W
  u16* Xb    = (u16*)(ws + ((size_t)8  << 20));   //  8..12MB x bf16
  u16* Qb    = (u16*)(ws + ((size_t)12 << 20));   // 12..16MB Q bf16
  u16* Kb    = (u16*)(ws + ((size_t)16 << 20));   // 16..20MB K bf16
  u16* Vb    = (u16*)(ws + ((size_t)20 << 20));   // 20..24MB V bf16
  u16* Vt    = (u16*)(ws + ((size_t)24 << 20));   // 24..28MB V^T bf16
  u16* AOb   = (u16*)(ws + ((size_t)28 << 20));   // 28..32MB attn out bf16
  float* Prt = (float*)(ws + ((size_t)32 << 20)); // 32..68MB split-K partials

  // 1) fused densify (blocks 0..2047) + x->bf16 (blocks 2048..3071)
  prep_bf16<<<dim3(3072, 1, 1), 256, 0, stream>>>(wq, wk, wv, wo, x, Wd, Xb);

  // 2) Q/K/V projections: BM=128, BN=64 -> 768 blocks (3/CU)
  gemm_bf16_nt<128, 64, 1><<<dim3(DIM / 64, (BATCH * NSEQ) / 128, 3), 256, 0, stream>>>(
      Xb, Wd, bq, bk, bv, Qb, Kb, Vb);

  // 3) V -> V^T per (b,h)
  transpose_v<<<dim3(NSEQ / 256, NHEAD, BATCH), 256, 0, stream>>>(Vb, Vt);

  // 4) split-K causal attention: 40 (qt,chunk) pairs per (b,h),
  //    stage-all + barrier-free loop; qt<4 writes AOb directly
  attn_split<<<dim3(40, NHEAD, BATCH), 256, 0, stream>>>(Qb, Kb, Vt, Prt, AOb);

  // 5) merge partials -> bf16 (qt >= 4 only)
  attn_merge<<<dim3(12, NHEAD, BATCH), 256, 0, stream>>>(Prt, AOb);

  // 6) output projection: BM=64, BN=64 -> 512 blocks (2/CU)
  gemm_bf16_nt<64, 64, 0><<<dim3(DIM / 64, (BATCH * NSEQ) / 64, 1), 256, 0, stream>>>(
      AOb, Wd + (size_t)3 * DIM * DIM, bo, bo, bo, d_out, d_out, d_out);
}

// Round 9
// 83.258 us; speedup vs baseline: 1.3809x; 1.0345x over previous
//
#include <hip/hip_runtime.h>
#include <hip/hip_bf16.h>

#define DIM   1024
#define NSEQ  1024
#define BATCH 2
#define NHEAD 16
#define DH    64

typedef unsigned short u16;
typedef __attribute__((ext_vector_type(8))) short  short8;
typedef __attribute__((ext_vector_type(4))) float  f32x4;
typedef __attribute__((ext_vector_type(8))) unsigned short u16x8;
typedef __attribute__((ext_vector_type(4))) unsigned short u16x4;

// log2(e) / sqrt(DH)
#define EXP_SCALE 0.18033688011112042f
// partial slot: 64x64 O (4096) + m (64) + l (64), padded
#define SLOT 4352

__device__ __forceinline__ u16 f2bf(float f) {
  union { float f; unsigned u; } v; v.f = f;
  unsigned r = v.u + 0x7FFFu + ((v.u >> 16) & 1u);   // RNE
  return (u16)(r >> 16);
}

#define GLD(src, dst)                                                          \
  __builtin_amdgcn_global_load_lds(                                           \
      (const __attribute__((address_space(1))) void*)(src),                   \
      (__attribute__((address_space(3))) void*)(dst), 16, 0, 0)

// ---------------------------------------------------------------------------
// Fused prep: densify circulant weights -> bf16 dense (blocks 0..2047),
// x fp32 -> bf16 (blocks 2048..3071).
// ---------------------------------------------------------------------------
__global__ __launch_bounds__(256) void prep_bf16(
    const float* __restrict__ wq, const float* __restrict__ wk,
    const float* __restrict__ wv, const float* __restrict__ wo,
    const float* __restrict__ x,
    u16* __restrict__ Wd, u16* __restrict__ Xb) {
  const int bid = blockIdx.x;
  if (bid < 2048) {
    const int z = bid >> 9;
    const float* w = (z == 0) ? wq : (z == 1) ? wk : (z == 2) ? wv : wo;
    u16* out = Wd + (size_t)z * DIM * DIM;
    const int idx8 = (bid & 511) * 256 + threadIdx.x;
    const int r = idx8 >> 7;
    const int q = idx8 & 127;
    const int p = r >> 3, a = r & 7;
    const float* wrow = w + (size_t)(p * 128 + q) * 8;
    const float4 w0 = *(const float4*)(wrow);
    const float4 w1 = *(const float4*)(wrow + 4);
    const float wv8[8] = {w0.x, w0.y, w0.z, w0.w, w1.x, w1.y, w1.z, w1.w};
    u16x8 o;
#pragma unroll
    for (int j = 0; j < 8; ++j) o[j] = f2bf(wv8[(a - j) & 7]);
    ((u16x8*)out)[idx8] = o;
  } else {
    const int i = (bid - 2048) * 256 + threadIdx.x;
    const float4 a = ((const float4*)x)[2 * i];
    const float4 b = ((const float4*)x)[2 * i + 1];
    u16x8 o;
    o[0] = f2bf(a.x); o[1] = f2bf(a.y); o[2] = f2bf(a.z); o[3] = f2bf(a.w);
    o[4] = f2bf(b.x); o[5] = f2bf(b.y); o[6] = f2bf(b.z); o[7] = f2bf(b.w);
    ((u16x8*)Xb)[i] = o;
  }
}

// ---------------------------------------------------------------------------
// Fused QKV GEMM: one block computes Q, K, V tiles for a (64-seq, 1-head)
// position. A(X) tile staged ONCE per K-step, shared across the 3 weights.
// BM=64, BN=64(=DH), BK=32, 256 thr = 4 waves (2x2), 2-phase dbuf.
// Q,K written row-major bf16; V written TRANSPOSED into Vt[b][h][dh][n].
// ---------------------------------------------------------------------------
__global__ __launch_bounds__(256, 2) void gemm_qkv(
    const u16* __restrict__ A, const u16* __restrict__ Wd,
    const float* __restrict__ bq, const float* __restrict__ bk,
    const float* __restrict__ bv,
    u16* __restrict__ Qb, u16* __restrict__ Kb, u16* __restrict__ Vt) {
  __shared__ u16 As[2][64 * 32];
  __shared__ u16 Bs[2][3 * 64 * 32];

  const int tid  = threadIdx.x;
  const int w    = tid >> 6, lane = tid & 63;
  const int nb   = blockIdx.x * 64;          // feature base = head * 64
  const int mb   = blockIdx.y * 64;          // seq base (over BATCH*NSEQ)

  f32x4 acc[3][2][2] = {};

  const int m0 = (w >> 1) * 32, n0 = (w & 1) * 32;
  const int lr = lane & 15, lk = (lane >> 4) * 8;

  // staging: row = w*16 + lane/4, kcol = (lane&3)*8; chunk-block cb -> cb*512
  const int srow = w * 16 + (lane >> 2), skc = (lane & 3) * 8;
  const u16* Ap = A + (size_t)(mb + srow) * DIM + skc;
  const u16* Wp = Wd + (size_t)(nb + srow) * DIM + skc;

#define STAGE(buf, k0)                                                         \
  do {                                                                         \
    GLD(Ap + (k0), As[buf] + w * 512);                                         \
    _Pragma("unroll")                                                          \
    for (int i = 0; i < 3; ++i)                                                \
      GLD(Wp + (size_t)i * DIM * DIM + (k0), Bs[buf] + (i * 4 + w) * 512);     \
  } while (0)

  STAGE(0, 0);
  __syncthreads();
  int cur = 0;
  for (int k0 = 0; k0 < DIM; k0 += 32) {
    if (k0 + 32 < DIM) STAGE(cur ^ 1, k0 + 32);

    short8 a[2], b[3][2];
#pragma unroll
    for (int mi = 0; mi < 2; ++mi)
      a[mi] = *(const short8*)&As[cur][(m0 + mi * 16 + lr) * 32 + lk];
#pragma unroll
    for (int z = 0; z < 3; ++z)
#pragma unroll
      for (int ni = 0; ni < 2; ++ni)
        b[z][ni] = *(const short8*)
            &Bs[cur][z * 2048 + (n0 + ni * 16 + lr) * 32 + lk];
#pragma unroll
    for (int z = 0; z < 3; ++z)
#pragma unroll
      for (int mi = 0; mi < 2; ++mi)
#pragma unroll
        for (int ni = 0; ni < 2; ++ni)
          acc[z][mi][ni] = __builtin_amdgcn_mfma_f32_16x16x32_bf16(
              a[mi], b[z][ni], acc[z][mi][ni], 0, 0, 0);

    __syncthreads();
    cur ^= 1;
  }
#undef STAGE

  // epilogue: C/D layout col(lane&15)=N(feature), row=(lane>>4)*4+j=M(seq)
  const int col = lane & 15, rq4 = (lane >> 4) * 4;

  // Q (z=0), K (z=1): row-major bf16
#pragma unroll
  for (int z = 0; z < 2; ++z) {
    u16* C = z ? Kb : Qb;
    const float* bias = z ? bk : bq;
#pragma unroll
    for (int ni = 0; ni < 2; ++ni) {
      const int gc = nb + n0 + ni * 16 + col;
      const float bb = bias[gc];
#pragma unroll
      for (int mi = 0; mi < 2; ++mi) {
        const size_t rbase = (size_t)(mb + m0 + mi * 16 + rq4) * DIM + gc;
#pragma unroll
        for (int j = 0; j < 4; ++j)
          C[rbase + (size_t)j * DIM] = f2bf(acc[z][mi][ni][j] + bb);
      }
    }
  }
  // V (z=2): transposed into Vt[(b*NHEAD+h)*DH + dh][n]
  {
    const int b = mb >> 10;                  // batch
    const int h = blockIdx.x;                // head (BN == DH)
    const int nbase = (mb & (NSEQ - 1)) + m0;
#pragma unroll
    for (int ni = 0; ni < 2; ++ni) {
      const int dh = n0 + ni * 16 + col;
      const float bb = bv[nb + dh];
      u16* vrow = Vt + ((size_t)(b * NHEAD + h) * DH + dh) * NSEQ;
#pragma unroll
      for (int mi = 0; mi < 2; ++mi) {
        const int nn = nbase + mi * 16 + rq4;
        u16x4 o;
#pragma unroll
        for (int j = 0; j < 4; ++j) o[j] = f2bf(acc[2][mi][ni][j] + bb);
        *(u16x4*)(vrow + nn) = o;
      }
    }
  }
}

// ---------------------------------------------------------------------------
// bf16 MFMA GEMM (NT) + bias, templated tile, 2-phase double-buffered.
// Used for the output projection.
// ---------------------------------------------------------------------------
template <int BM, int BN, int BFOUT>
__global__ __launch_bounds__(256) void gemm_bf16_nt(
    const u16* __restrict__ A, const u16* __restrict__ Wbase,
    const float* __restrict__ b0,
    void* __restrict__ C0) {
  constexpr int MR = BM / 32, NR = BN / 32;
  constexpr int CA = BM / 64, CB = BN / 64;

  const u16* W      = Wbase;
  const float* bias = b0;
  void* C           = C0;

  __shared__ u16 As[2][BM * 32];
  __shared__ u16 Bs[2][BN * 32];

  const int tid  = threadIdx.x;
  const int w    = tid >> 6, lane = tid & 63;
  const int mb   = blockIdx.y * BM, nb = blockIdx.x * BN;

  f32x4 acc[MR][NR] = {};

  const int m0 = (w >> 1) * (BM / 2), n0 = (w & 1) * (BN / 2);
  const int lr = lane & 15, lk = (lane >> 4) * 8;

  const int srow = lane >> 2, skc = (lane & 3) * 8;

#define STAGE(buf, k0)                                                         \
  do {                                                                         \
    _Pragma("unroll")                                                          \
    for (int i = 0; i < CA; ++i) {                                             \
      const int cb = w * CA + i;                                               \
      GLD(A + (size_t)(mb + cb * 16 + srow) * DIM + (k0) + skc,                \
          As[buf] + cb * 512);                                                 \
    }                                                                          \
    _Pragma("unroll")                                                          \
    for (int i = 0; i < CB; ++i) {                                             \
      const int cb = w * CB + i;                                               \
      GLD(W + (size_t)(nb + cb * 16 + srow) * DIM + (k0) + skc,                \
          Bs[buf] + cb * 512);                                                 \
    }                                                                          \
  } while (0)

  STAGE(0, 0);
  __syncthreads();
  int cur = 0;
  for (int k0 = 0; k0 < DIM; k0 += 32) {
    if (k0 + 32 < DIM) STAGE(cur ^ 1, k0 + 32);

    short8 a[MR], b[NR];
#pragma unroll
    for (int mi = 0; mi < MR; ++mi)
      a[mi] = *(const short8*)&As[cur][(m0 + mi * 16 + lr) * 32 + lk];
#pragma unroll
    for (int ni = 0; ni < NR; ++ni)
      b[ni] = *(const short8*)&Bs[cur][(n0 + ni * 16 + lr) * 32 + lk];
#pragma unroll
    for (int mi = 0; mi < MR; ++mi)
#pragma unroll
      for (int ni = 0; ni < NR; ++ni)
        acc[mi][ni] = __builtin_amdgcn_mfma_f32_16x16x32_bf16(
            a[mi], b[ni], acc[mi][ni], 0, 0, 0);

    __syncthreads();
    cur ^= 1;
  }
#undef STAGE

  const int col = lane & 15, rq = (lane >> 4) * 4;
#pragma unroll
  for (int ni = 0; ni < NR; ++ni) {
    const int gc = nb + n0 + ni * 16 + col;
    const float bv = bias[gc];
#pragma unroll
    for (int mi = 0; mi < MR; ++mi) {
      const size_t rbase = (size_t)(mb + m0 + mi * 16 + rq) * DIM + gc;
#pragma unroll
      for (int j = 0; j < 4; ++j) {
        const float v = acc[mi][ni][j] + bv;
        if (BFOUT) ((u16*)C)[rbase + (size_t)j * DIM] = f2bf(v);
        else       ((float*)C)[rbase + (size_t)j * DIM] = v;
      }
    }
  }
}

// ---------------------------------------------------------------------------
// Split-K causal flash attention: stage ALL (<=4) K/V tiles up front via
// global_load_lds, ONE __syncthreads, then a barrier-free inner loop.
// Block = (qt, chunk of <=4 KV tiles) x (h, b); 4 waves x 16 q.
// Swapped QK^T -> lane-local softmax; PV via V^T frags + P in wave LDS.
// nc==1 (qt<4): write bf16 AOb directly.  Else write f32 partial slot.
// ---------------------------------------------------------------------------
__global__ __launch_bounds__(256, 4) void attn_split(
    const u16* __restrict__ Qg, const u16* __restrict__ Kg,
    const u16* __restrict__ Vt, float* __restrict__ Part,
    u16* __restrict__ AOb) {
  // blockIdx.x -> (qt, cc), heavy qt first
  int idx = blockIdx.x, qt = 0, cc = 0;
  for (int t = 15; t >= 0; --t) {
    const int nc = (t >> 2) + 1;
    if (idx < nc) { qt = t; cc = idx; break; }
    idx -= nc;
  }
  const int h = blockIdx.y, b = blockIdx.z;
  const int tid = threadIdx.x;
  const int w  = tid >> 6, l = tid & 63;
  const int lr = l & 15, lg = l >> 4;

  __shared__ u16 Klds[4][64 * 64];     // [key][dh], xor-swizzled (16B granule)
  __shared__ u16 Vlds[4][64 * 64];     // [dh][key], xor-swizzled
  __shared__ u16 Plds[4][16 * 64];     // per-wave P [q][key], swizzled

  const int qg = qt * 64 + w * 16 + lr;
  const size_t base_bh = (size_t)b * NSEQ * DIM + (size_t)h * DH;
  const size_t vt_bh   = (size_t)(b * NHEAD + h) * DH * NSEQ;

  short8 qf[2];
#pragma unroll
  for (int c = 0; c < 2; ++c)
    qf[c] = *(const short8*)(Qg + base_bh + (size_t)qg * DIM + c * 32 + lg * 8);

  f32x4 acc_o[4] = {};
  float m_run = -1e30f, l_run = 0.f;
  char* pbase = (char*)Plds[w];
  const int psw = (lr & 7) << 4;

  const int srow8 = l >> 3;
  const int sj    = l & 7;

  const int kt0 = cc * 4;
  const int nt  = min(kt0 + 4, qt + 1) - kt0;    // 1..4 tiles

  // --- stage ALL tiles up front (uniform branches), one barrier ---
#pragma unroll
  for (int t = 0; t < 4; ++t) {
    if (t < nt) {
      const int kt = kt0 + t;
#pragma unroll
      for (int i = 0; i < 2; ++i) {
        const int cb  = w * 2 + i;
        const int row = cb * 8 + srow8;
        const int c16 = sj ^ (row & 7);
        GLD(Kg + base_bh + (size_t)(kt * 64 + row) * DIM + c16 * 8,
            Klds[t] + cb * 512);
        GLD(Vt + vt_bh + (size_t)row * NSEQ + kt * 64 + c16 * 8,
            Vlds[t] + cb * 512);
      }
    }
  }
  __syncthreads();     // all K/V tiles resident; no further barriers

  for (int it = 0; it < nt; ++it) {
    const int kt = kt0 + it;

    // --- QK^T: S^T subtiles (rows=key, col=q) from swizzled Klds ---
    f32x4 s[4] = {};
#pragma unroll
    for (int t16 = 0; t16 < 4; ++t16) {
      const int row = t16 * 16 + lr;
#pragma unroll
      for (int c = 0; c < 2; ++c) {
        const int c16 = (c * 4 + lg) ^ (row & 7);
        const short8 kf = *(const short8*)
            ((const char*)Klds[it] + row * 128 + c16 * 16);
        s[t16] = __builtin_amdgcn_mfma_f32_16x16x32_bf16(kf, qf[c], s[t16], 0, 0, 0);
      }
    }

    // --- mask (diagonal tile only) + online softmax (lane-local q) ---
    const bool diag = (kt == qt);
    float mloc = -1e30f;
#pragma unroll
    for (int t16 = 0; t16 < 4; ++t16)
#pragma unroll
      for (int j = 0; j < 4; ++j) {
        float v = s[t16][j];
        if (diag && (kt * 64 + t16 * 16 + lg * 4 + j) > qg) v = -1e30f;
        s[t16][j] = v;
        mloc = fmaxf(mloc, v);
      }
    mloc = fmaxf(mloc, __shfl_xor(mloc, 16));
    mloc = fmaxf(mloc, __shfl_xor(mloc, 32));
    const float m_new = fmaxf(m_run, mloc);
    const float a = exp2f((m_run - m_new) * EXP_SCALE);
    float psum = 0.f;
    u16x4 pk[4];
#pragma unroll
    for (int t16 = 0; t16 < 4; ++t16)
#pragma unroll
      for (int j = 0; j < 4; ++j) {
        const float p = exp2f((s[t16][j] - m_new) * EXP_SCALE);
        psum += p;
        pk[t16][j] = f2bf(p);
      }
    psum += __shfl_xor(psum, 16);
    psum += __shfl_xor(psum, 32);
    l_run = l_run * a + psum;
    m_run = m_new;
#pragma unroll
    for (int d = 0; d < 4; ++d) acc_o[d] *= a;

    // --- P -> wave-private LDS (swizzled), then PV from swizzled Vlds ---
#pragma unroll
    for (int t16 = 0; t16 < 4; ++t16)
      *(u16x4*)(pbase + lr * 128 + ((t16 * 32 + lg * 8) ^ psw)) = pk[t16];

#pragma unroll
    for (int c = 0; c < 2; ++c) {
      const short8 pf = *(const short8*)
          (pbase + lr * 128 + ((c * 64 + lg * 16) ^ psw));
#pragma unroll
      for (int d = 0; d < 4; ++d) {
        const int dh = d * 16 + lr;
        const int c16 = (c * 4 + lg) ^ (dh & 7);
        const short8 vf = *(const short8*)
            ((const char*)Vlds[it] + dh * 128 + c16 * 16);
        acc_o[d] = __builtin_amdgcn_mfma_f32_16x16x32_bf16(vf, pf, acc_o[d], 0, 0, 0);
      }
    }
  }

  const int ql = w * 16 + lr;
  if (qt < 4) {
    const float inv = 1.f / l_run;
    u16* Op = AOb + (size_t)(b * NSEQ + qt * 64 + ql) * DIM + (size_t)h * DH;
#pragma unroll
    for (int d = 0; d < 4; ++d) {
      u16x4 o;
      o[0] = f2bf(acc_o[d][0] * inv); o[1] = f2bf(acc_o[d][1] * inv);
      o[2] = f2bf(acc_o[d][2] * inv); o[3] = f2bf(acc_o[d][3] * inv);
      *(u16x4*)(Op + d * 16 + lg * 4) = o;
    }
  } else {
    float* slot = Part + (((size_t)(b * NHEAD + h) * 16 + qt) * 4 + cc) * SLOT;
#pragma unroll
    for (int d = 0; d < 4; ++d)
      *(f32x4*)(slot + ql * 64 + d * 16 + lg * 4) = acc_o[d];
    if (lg == 0) {
      slot[4096 + ql] = m_run;
      slot[4160 + ql] = l_run;
    }
  }
}

// ---------------------------------------------------------------------------
// Merge split-K partials -> bf16 attention output (qt >= 4 only).
// ---------------------------------------------------------------------------
__global__ __launch_bounds__(256) void attn_merge(
    const float* __restrict__ Part, u16* __restrict__ AOb) {
  const int qt = blockIdx.x + 4, h = blockIdx.y, b = blockIdx.z;
  const int t = threadIdx.x;
  const int q = t >> 2, quad = t & 3;
  const int nc = (qt >> 2) + 1;
  const float* base = Part + ((size_t)(b * NHEAD + h) * 16 + qt) * 4 * SLOT;

  float mv[4], lv[4];
  float M = -1e30f;
  for (int c = 0; c < nc; ++c) {
    mv[c] = base[c * SLOT + 4096 + q];
    lv[c] = base[c * SLOT + 4160 + q];
    M = fmaxf(M, mv[c]);
  }
  float L = 0.f, fc[4];
  for (int c = 0; c < nc; ++c) {
    fc[c] = exp2f((mv[c] - M) * EXP_SCALE);
    L += lv[c] * fc[c];
  }
  const float inv = 1.f / L;

  float o[16] = {};
  for (int c = 0; c < nc; ++c) {
    const float* op = base + c * SLOT + q * 64 + quad * 16;
    const float f = fc[c];
#pragma unroll
    for (int i = 0; i < 4; ++i) {
      const f32x4 v = *(const f32x4*)(op + i * 4);
      o[i * 4 + 0] += f * v[0]; o[i * 4 + 1] += f * v[1];
      o[i * 4 + 2] += f * v[2]; o[i * 4 + 3] += f * v[3];
    }
  }

  u16* dst = AOb + (size_t)(b * NSEQ + qt * 64 + q) * DIM + h * DH + quad * 16;
  u16x8 o0, o1;
#pragma unroll
  for (int i = 0; i < 8; ++i) { o0[i] = f2bf(o[i] * inv); o1[i] = f2bf(o[8 + i] * inv); }
  *(u16x8*)(dst)     = o0;
  *(u16x8*)(dst + 8) = o1;
}

// ---------------------------------------------------------------------------
extern "C" void kernel_launch(void* const* d_in, const int* in_sizes, int n_in,
                              void* d_out, int out_size, void* d_ws, size_t ws_size,
                              hipStream_t stream) {
  const float* x  = (const float*)d_in[0];
  // d_in[1] = causal mask (ignored; mask is m > n analytically)
  const float* wq = (const float*)d_in[2];
  const float* bq = (const float*)d_in[3];
  const float* wk = (const float*)d_in[4];
  const float* bk = (const float*)d_in[5];
  const float* wv = (const float*)d_in[6];
  const float* bv = (const float*)d_in[7];
  const float* wo = (const float*)d_in[8];
  const float* bo = (const float*)d_in[9];

  char* ws = (char*)d_ws;
  u16* Wd    = (u16*)(ws);                        //  0..8MB  4 dense bf16 W
  u16* Xb    = (u16*)(ws + ((size_t)8  << 20));   //  8..12MB x bf16
  u16* Qb    = (u16*)(ws + ((size_t)12 << 20));   // 12..16MB Q bf16
  u16* Kb    = (u16*)(ws + ((size_t)16 << 20));   // 16..20MB K bf16
  u16* Vt    = (u16*)(ws + ((size_t)24 << 20));   // 24..28MB V^T bf16
  u16* AOb   = (u16*)(ws + ((size_t)28 << 20));   // 28..32MB attn out bf16
  float* Prt = (float*)(ws + ((size_t)32 << 20)); // 32..68MB split-K partials

  // 1) fused densify (blocks 0..2047) + x->bf16 (blocks 2048..3071)
  prep_bf16<<<dim3(3072, 1, 1), 256, 0, stream>>>(wq, wk, wv, wo, x, Wd, Xb);

  // 2) fused QKV projection: A-tile shared across 3 weights; V written
  //    transposed directly (no transpose_v pass). 512 blocks = 2/CU.
  gemm_qkv<<<dim3(NHEAD, (BATCH * NSEQ) / 64, 1), 256, 0, stream>>>(
      Xb, Wd, bq, bk, bv, Qb, Kb, Vt);

  // 3) split-K causal attention: 40 (qt,chunk) pairs per (b,h),
  //    stage-all + barrier-free loop; qt<4 writes AOb directly
  attn_split<<<dim3(40, NHEAD, BATCH), 256, 0, stream>>>(Qb, Kb, Vt, Prt, AOb);

  // 4) merge partials -> bf16 (qt >= 4 only)
  attn_merge<<<dim3(12, NHEAD, BATCH), 256, 0, stream>>>(Prt, AOb);

  // 5) output projection: BM=64, BN=64 -> 512 blocks (2/CU)
  gemm_bf16_nt<64, 64, 0><<<dim3(DIM / 64, (BATCH * NSEQ) / 64, 1), 256, 0, stream>>>(
      AOb, Wd + (size_t)3 * DIM * DIM, bo, d_out);
}